// Round 1
// baseline (1188.203 us; speedup 1.0000x reference)
//
#include <hip/hip_runtime.h>

typedef unsigned short ushort_t;
typedef __attribute__((ext_vector_type(8))) short bf16x8;
typedef __attribute__((ext_vector_type(4))) float f32x4;
typedef __attribute__((ext_vector_type(4))) unsigned short u16x4;

#define DEV __device__ __forceinline__

typedef const __attribute__((address_space(1))) void GV;
typedef __attribute__((address_space(3))) void SV;

DEV void gl_lds16(const ushort_t* g, ushort_t* l) {
    __builtin_amdgcn_global_load_lds((GV*)g, (SV*)l, 16, 0, 0);
}

DEV float bf2f(unsigned short u) {
    union { unsigned u; float f; } c; c.u = ((unsigned)u) << 16; return c.f;
}
DEV unsigned short f2bf(float f) {
    union { float f; unsigned u; } c; c.f = f;
    unsigned u = c.u + 0x7fffu + ((c.u >> 16) & 1u);
    return (unsigned short)(u >> 16);
}

DEV f32x4 mfma32(bf16x8 a, bf16x8 b, f32x4 c) {
    return __builtin_amdgcn_mfma_f32_16x16x32_bf16(a, b, c, 0, 0, 0);
}

// ---------------- generic fp32 -> bf16 convert ----------------
__global__ void cvt_kernel(const float* __restrict__ in, ushort_t* __restrict__ out, int n4) {
    for (int i = blockIdx.x * 256 + threadIdx.x; i < n4; i += gridDim.x * 256) {
        f32x4 v = *(const f32x4*)(in + (size_t)i * 4);
        u16x4 o;
        #pragma unroll
        for (int j = 0; j < 4; j++) o[j] = f2bf(v[j]);
        *(u16x4*)(out + (size_t)i * 4) = o;
    }
}

// ---------------- A_norm: softplus + row-normalize, pad to 256 rows ----------------
__global__ void anorm_kernel(const float* __restrict__ wm, ushort_t* __restrict__ apad) {
    int row = blockIdx.x;           // 0..255
    int lane = threadIdx.x;         // 64 threads
    if (row >= 192) {
        apad[row * 192 + lane] = 0;
        apad[row * 192 + lane + 64] = 0;
        apad[row * 192 + lane + 128] = 0;
        return;
    }
    float x0 = wm[row * 192 + lane];
    float x1 = wm[row * 192 + lane + 64];
    float x2 = wm[row * 192 + lane + 128];
    float s0 = (x0 > 20.f) ? x0 : log1pf(expf(x0));
    float s1 = (x1 > 20.f) ? x1 : log1pf(expf(x1));
    float s2 = (x2 > 20.f) ? x2 : log1pf(expf(x2));
    float t = s0 + s1 + s2;
    #pragma unroll
    for (int m = 1; m < 64; m <<= 1) t += __shfl_xor(t, m);
    float inv = 1.f / t;
    apad[row * 192 + lane]       = f2bf(s0 * inv);
    apad[row * 192 + lane + 64]  = f2bf(s1 * inv);
    apad[row * 192 + lane + 128] = f2bf(s2 * inv);
}

// ---------------- diffproj: diff_emb @ w_diff.T + b_diff (fp32) ----------------
__global__ void diffproj_kernel(const float* __restrict__ emb, const float* __restrict__ w,
                                const float* __restrict__ bias, float* __restrict__ out) {
    int id = blockIdx.x * 256 + threadIdx.x;   // 65536 = 64*1024
    int b = id >> 10, n = id & 1023;
    const float* e = emb + b * 256;
    const float* wr = w + (size_t)n * 256;
    float acc = bias[n];
    for (int k2 = 0; k2 < 256; k2++) acc += e[k2] * wr[k2];
    out[id] = acc;
}

// ---------------- x1 = x + diffproj (broadcast over L), write bf16 ----------------
__global__ void x1_kernel(const float* __restrict__ x, const float* __restrict__ dp,
                          ushort_t* __restrict__ out) {
    const size_t N4 = 12288ULL * 1024 / 4;
    for (size_t i = (size_t)blockIdx.x * 256 + threadIdx.x; i < N4; i += (size_t)gridDim.x * 256) {
        size_t e = i * 4;
        size_t row = e >> 10;
        int d = (int)(e & 1023);
        int bb = (int)(row / 192);
        f32x4 xv = *(const f32x4*)(x + e);
        u16x4 o4;
        #pragma unroll
        for (int j = 0; j < 4; j++) o4[j] = f2bf(xv[j] + dp[bb * 1024 + d + j]);
        *(u16x4*)(out + e) = o4;
    }
}

// ---------------- transpose: values[b][j][d] -> valuesT[b][d][j] (bf16) ----------------
__global__ __launch_bounds__(256) void transp_kernel(const ushort_t* __restrict__ in,
                                                     ushort_t* __restrict__ out) {
    __shared__ ushort_t t[32][33];
    int b = blockIdx.z, jt = blockIdx.y, dt = blockIdx.x;
    int tx = threadIdx.x & 31, ty = threadIdx.x >> 5;
    size_t ib = (size_t)b * 192 * 1024;
    #pragma unroll
    for (int i = 0; i < 4; i++) {
        int j = ty + i * 8;
        t[j][tx] = in[ib + (size_t)(jt * 32 + j) * 1024 + dt * 32 + tx];
    }
    __syncthreads();
    size_t ob = (size_t)b * 1024 * 192;
    #pragma unroll
    for (int i = 0; i < 4; i++) {
        int d = ty + i * 8;
        out[ob + (size_t)(dt * 32 + d) * 192 + jt * 32 + tx] = t[tx][d];
    }
}

// ---------------- GEMM: C[M,N] = epi(A[M,K] @ W[N,K]^T), 128x128 tile, m97 structure ----
// EPI: 0 plain->bf16, 1 +bias->bf16, 2 gelu(x+bias)->bf16, 3 +bias+resid->bf16,
//      4 *scale->bf16, 5 final: leaky(x+bias), split out/skip -> f32 d_out
template<int EPI>
__global__ __launch_bounds__(256) void gemm_bt(
    const ushort_t* __restrict__ A, int lda, long long sAz,
    const ushort_t* __restrict__ W, int ldw, long long sWz,
    void* __restrict__ Cv, int ldc, long long sCz,
    int Mbound, int K,
    const float* __restrict__ bias,
    const ushort_t* __restrict__ resid,
    float scale,
    const float* __restrict__ resf)
{
    __shared__ ushort_t As[4096];
    __shared__ ushort_t Bs[4096];
    const int tid = threadIdx.x;
    const int wave = tid >> 6, lane = tid & 63, l15 = lane & 15, g = lane >> 4;
    const int wm = wave >> 1, wn = wave & 1;
    const ushort_t* Ab = A + (size_t)blockIdx.z * sAz + (size_t)blockIdx.y * 128 * lda;
    const ushort_t* Wb = W + (size_t)blockIdx.z * sWz + (size_t)blockIdx.x * 128 * ldw;
    const int ob = wave * 1024 + lane * 16;   // byte within 4KB half-tile
    const int r0 = ob >> 6, c0 = (ob & 63) >> 1;
    f32x4 acc[4][4] = {};
    for (int k0 = 0; k0 < K; k0 += 32) {
        gl_lds16(Ab + (size_t)r0 * lda + (k0 + c0), As + wave * 512);
        gl_lds16(Ab + (size_t)(r0 + 64) * lda + (k0 + c0), As + 2048 + wave * 512);
        gl_lds16(Wb + (size_t)r0 * ldw + (k0 + c0), Bs + wave * 512);
        gl_lds16(Wb + (size_t)(r0 + 64) * ldw + (k0 + c0), Bs + 2048 + wave * 512);
        __syncthreads();
        bf16x8 af[4], bfr[4];
        const ushort_t* Ar = &As[(wm * 64 + l15) * 32 + g * 8];
        const ushort_t* Br = &Bs[(wn * 64 + l15) * 32 + g * 8];
        #pragma unroll
        for (int i = 0; i < 4; i++) {
            af[i]  = *(const bf16x8*)(Ar + i * 512);
            bfr[i] = *(const bf16x8*)(Br + i * 512);
        }
        #pragma unroll
        for (int mi = 0; mi < 4; mi++)
            #pragma unroll
            for (int ni = 0; ni < 4; ni++)
                acc[mi][ni] = mfma32(af[mi], bfr[ni], acc[mi][ni]);
        __syncthreads();
    }
    // epilogue
    const int Rbase = blockIdx.y * 128 + wm * 64;
    const int Cbase = blockIdx.x * 128 + wn * 64;
    #pragma unroll
    for (int mi = 0; mi < 4; mi++) {
        #pragma unroll
        for (int ni = 0; ni < 4; ni++) {
            int Cc = Cbase + ni * 16 + l15;
            float bval = 0.f;
            if (EPI == 1 || EPI == 2 || EPI == 3 || EPI == 5) bval = bias[Cc];
            #pragma unroll
            for (int q = 0; q < 4; q++) {
                int R = Rbase + mi * 16 + g * 4 + q;
                if (R < Mbound) {
                    float t = acc[mi][ni][q];
                    if (EPI == 5) {
                        t += bval;
                        t = (t >= 0.f) ? t : 0.4f * t;
                        float* Of = (float*)Cv;
                        if (Cc < 1024)
                            Of[(size_t)R * 1024 + Cc] = (resf[(size_t)R * 1024 + Cc] + t) * 0.70710678118654752f;
                        else
                            Of[12582912ULL + (size_t)R * 1024 + (Cc - 1024)] = t;
                    } else {
                        ushort_t* Co = (ushort_t*)Cv + (size_t)blockIdx.z * sCz;
                        if (EPI == 1) t += bval;
                        if (EPI == 2) { t += bval; t = 0.5f * t * (1.f + erff(t * 0.70710678118654752f)); }
                        if (EPI == 3) { t += bval + bf2f(resid[(size_t)R * ldc + Cc]); }
                        if (EPI == 4) { t *= scale; }
                        Co[(size_t)R * ldc + Cc] = f2bf(t);
                    }
                }
            }
        }
    }
}

// ---------------- block reduce (256 threads) for LN ----------------
DEV void red2(float& a, float& b) {
    #pragma unroll
    for (int m = 1; m < 64; m <<= 1) { a += __shfl_xor(a, m); b += __shfl_xor(b, m); }
    __shared__ float sa[4], sb[4];
    int w = threadIdx.x >> 6;
    __syncthreads();
    if ((threadIdx.x & 63) == 0) { sa[w] = a; sb[w] = b; }
    __syncthreads();
    a = sa[0] + sa[1] + sa[2] + sa[3];
    b = sb[0] + sb[1] + sb[2] + sb[3];
}

// ---------------- LN (single) ----------------
__global__ __launch_bounds__(256) void ln_kernel(const ushort_t* __restrict__ in,
                                                 const float* __restrict__ gg, const float* __restrict__ bb,
                                                 ushort_t* __restrict__ out) {
    size_t row = blockIdx.x;
    int c0 = threadIdx.x * 4;
    u16x4 r4 = *(const u16x4*)(in + row * 1024 + c0);
    float x[4];
    float s = 0.f, sq = 0.f;
    #pragma unroll
    for (int j = 0; j < 4; j++) { x[j] = bf2f(r4[j]); s += x[j]; sq += x[j] * x[j]; }
    red2(s, sq);
    float m = s * (1.f / 1024.f);
    float var = sq * (1.f / 1024.f) - m * m;
    float rs = rsqrtf(var + 1e-5f);
    u16x4 o4;
    #pragma unroll
    for (int j = 0; j < 4; j++) o4[j] = f2bf((x[j] - m) * rs * gg[c0 + j] + bb[c0 + j]);
    *(u16x4*)(out + row * 1024 + c0) = o4;
}

// ---------------- double LN: ln(ln(x,g1,b1),g2,b2) ----------------
__global__ __launch_bounds__(256) void ln2_kernel(const ushort_t* __restrict__ in,
                                                  const float* __restrict__ g1, const float* __restrict__ b1,
                                                  const float* __restrict__ g2, const float* __restrict__ b2,
                                                  ushort_t* __restrict__ out) {
    size_t row = blockIdx.x;
    int c0 = threadIdx.x * 4;
    u16x4 r4 = *(const u16x4*)(in + row * 1024 + c0);
    float x[4];
    float s = 0.f, sq = 0.f;
    #pragma unroll
    for (int j = 0; j < 4; j++) { x[j] = bf2f(r4[j]); s += x[j]; sq += x[j] * x[j]; }
    red2(s, sq);
    float m = s * (1.f / 1024.f);
    float var = sq * (1.f / 1024.f) - m * m;
    float rs = rsqrtf(var + 1e-5f);
    float t[4];
    float s2 = 0.f, sq2 = 0.f;
    #pragma unroll
    for (int j = 0; j < 4; j++) {
        t[j] = (x[j] - m) * rs * g1[c0 + j] + b1[c0 + j];
        s2 += t[j]; sq2 += t[j] * t[j];
    }
    red2(s2, sq2);
    float m2 = s2 * (1.f / 1024.f);
    float var2 = sq2 * (1.f / 1024.f) - m2 * m2;
    float rs2 = rsqrtf(var2 + 1e-5f);
    u16x4 o4;
    #pragma unroll
    for (int j = 0; j < 4; j++) o4[j] = f2bf((t[j] - m2) * rs2 * g2[c0 + j] + b2[c0 + j]);
    *(u16x4*)(out + row * 1024 + c0) = o4;
}

// ---------------- LN(ln2) + gate: tanh(g)*sigmoid(f), out [rows][512] bf16 ----------------
__global__ __launch_bounds__(256) void lngate_kernel(const ushort_t* __restrict__ in,
                                                     const float* __restrict__ gg, const float* __restrict__ bb,
                                                     ushort_t* __restrict__ out) {
    __shared__ float buf[1024];
    size_t row = blockIdx.x;
    int c0 = threadIdx.x * 4;
    u16x4 r4 = *(const u16x4*)(in + row * 1024 + c0);
    float x[4];
    float s = 0.f, sq = 0.f;
    #pragma unroll
    for (int j = 0; j < 4; j++) { x[j] = bf2f(r4[j]); s += x[j]; sq += x[j] * x[j]; }
    red2(s, sq);
    float m = s * (1.f / 1024.f);
    float var = sq * (1.f / 1024.f) - m * m;
    float rs = rsqrtf(var + 1e-5f);
    #pragma unroll
    for (int j = 0; j < 4; j++) buf[c0 + j] = (x[j] - m) * rs * gg[c0 + j] + bb[c0 + j];
    __syncthreads();
    if (threadIdx.x < 128) {
        int c = threadIdx.x * 4;
        u16x4 o4;
        #pragma unroll
        for (int j = 0; j < 4; j++) {
            float gv = buf[c + j], fv = buf[c + j + 512];
            o4[j] = f2bf(tanhf(gv) * (1.f / (1.f + expf(-fv))));
        }
        *(u16x4*)(out + row * 512 + c) = o4;
    }
}

// ---------------- attention: per (qtile64, head, batch) block, MFMA QK^T/softmax/PV ----
__global__ __launch_bounds__(256) void attn_kernel(const ushort_t* __restrict__ q,
                                                   const ushort_t* __restrict__ k,
                                                   const ushort_t* __restrict__ v,
                                                   ushort_t* __restrict__ o) {
    __shared__ ushort_t vT[64][208];
    __shared__ ushort_t pS[4][16][208];
    const int tid = threadIdx.x, wave = tid >> 6, lane = tid & 63, l15 = lane & 15, g = lane >> 4;
    const int qb = blockIdx.x, h = blockIdx.y, b = blockIdx.z;
    const size_t base = (size_t)b * 192 * 1024 + h * 64;
    // stage v^T into LDS
    #pragma unroll
    for (int it = 0; it < 6; ++it) {
        int idx = it * 256 + tid;          // 0..1535 : j = idx/8, d8 = (idx%8)*8
        int j = idx >> 3, d8 = (idx & 7) * 8;
        bf16x8 vv = *(const bf16x8*)(v + base + (size_t)j * 1024 + d8);
        #pragma unroll
        for (int e = 0; e < 8; e++) vT[d8 + e][j] = (ushort_t)vv[e];
    }
    // QK^T (q is pre-scaled by 1/8)
    const int qrow = qb * 64 + wave * 16 + l15;
    bf16x8 aq[2];
    #pragma unroll
    for (int kk = 0; kk < 2; kk++)
        aq[kk] = *(const bf16x8*)(q + base + (size_t)qrow * 1024 + kk * 32 + g * 8);
    f32x4 s[12] = {};
    #pragma unroll
    for (int ni = 0; ni < 12; ni++) {
        #pragma unroll
        for (int kk = 0; kk < 2; kk++) {
            bf16x8 bk = *(const bf16x8*)(k + base + (size_t)(ni * 16 + l15) * 1024 + kk * 32 + g * 8);
            s[ni] = mfma32(aq[kk], bk, s[ni]);
        }
    }
    // wave-parallel softmax: row r = g*4+qq lives in lanes sharing g across l15 and 12 frags
    float sminv[4];
    #pragma unroll
    for (int qq = 0; qq < 4; qq++) {
        float m = s[0][qq];
        #pragma unroll
        for (int ni = 1; ni < 12; ni++) m = fmaxf(m, s[ni][qq]);
        #pragma unroll
        for (int msk = 1; msk < 16; msk <<= 1) m = fmaxf(m, __shfl_xor(m, msk));
        float sum = 0.f;
        #pragma unroll
        for (int ni = 0; ni < 12; ni++) {
            float p = expf(s[ni][qq] - m);
            s[ni][qq] = p;
            sum += p;
        }
        #pragma unroll
        for (int msk = 1; msk < 16; msk <<= 1) sum += __shfl_xor(sum, msk);
        sminv[qq] = 1.f / sum;
    }
    // write P (unnormalized) to LDS in A-frag order
    #pragma unroll
    for (int ni = 0; ni < 12; ni++)
        #pragma unroll
        for (int qq = 0; qq < 4; qq++)
            pS[wave][g * 4 + qq][ni * 16 + l15] = f2bf(s[ni][qq]);
    __syncthreads();
    // PV
    f32x4 oa[4] = {};
    #pragma unroll
    for (int ks = 0; ks < 6; ks++) {
        bf16x8 pa = *(const bf16x8*)(&pS[wave][l15][ks * 32 + g * 8]);
        #pragma unroll
        for (int di = 0; di < 4; di++) {
            bf16x8 bv = *(const bf16x8*)(&vT[di * 16 + l15][ks * 32 + g * 8]);
            oa[di] = mfma32(pa, bv, oa[di]);
        }
    }
    // write o (normalize by softmax sum)
    #pragma unroll
    for (int di = 0; di < 4; di++)
        #pragma unroll
        for (int qq = 0; qq < 4; qq++) {
            int row = qb * 64 + wave * 16 + g * 4 + qq;
            o[(size_t)b * 192 * 1024 + (size_t)row * 1024 + h * 64 + di * 16 + l15] =
                f2bf(oa[di][qq] * sminv[qq]);
        }
}

// =====================================================================================
extern "C" void kernel_launch(void* const* d_in, const int* in_sizes, int n_in,
                              void* d_out, int out_size, void* d_ws, size_t ws_size,
                              hipStream_t stream) {
    (void)in_sizes; (void)n_in; (void)out_size; (void)ws_size;
    const float* x_f     = (const float*)d_in[0];
    const float* conds   = (const float*)d_in[1];
    const float* demb    = (const float*)d_in[2];
    const float* w_diff  = (const float*)d_in[3];
    const float* b_diff  = (const float*)d_in[4];
    const float* w_cond  = (const float*)d_in[5];
    const float* b_cond  = (const float*)d_in[6];
    const float* wq      = (const float*)d_in[7];
    const float* wk      = (const float*)d_in[8];
    const float* wv      = (const float*)d_in[9];
    const float* wo      = (const float*)d_in[10];
    const float* bo      = (const float*)d_in[11];
    const float* ln1_g   = (const float*)d_in[12];
    const float* ln1_b   = (const float*)d_in[13];
    const float* ln2_g   = (const float*)d_in[14];
    const float* ln2_b   = (const float*)d_in[15];
    const float* w_out   = (const float*)d_in[16];
    const float* b_out   = (const float*)d_in[17];
    const float* enc_wv  = (const float*)d_in[18];
    const float* enc_bv  = (const float*)d_in[19];
    const float* enc_wo  = (const float*)d_in[20];
    const float* enc_bo  = (const float*)d_in[21];
    const float* wmat    = (const float*)d_in[22];
    const float* conv1_w = (const float*)d_in[23];
    const float* conv1_b = (const float*)d_in[24];
    const float* conv2_w = (const float*)d_in[25];
    const float* conv2_b = (const float*)d_in[26];
    const float* en1_g   = (const float*)d_in[27];
    const float* en1_b   = (const float*)d_in[28];
    const float* en2_g   = (const float*)d_in[29];
    const float* en2_b   = (const float*)d_in[30];

    char* ws = (char*)d_ws;
    size_t off = 0;
    auto nxt = [&](size_t b) { size_t r = off; off += (b + 255) & ~(size_t)255; return r; };

    const size_t RB = 12288ULL * 1024 * 2;   // one bf16 region [12288][1024]
    size_t o_wencv = nxt(1048576 * 2);
    size_t o_wenco = nxt(1048576 * 2);
    size_t o_conv1 = nxt(4194304 * 2);
    size_t o_conv2 = nxt(4194304 * 2);
    size_t o_wq    = nxt(1048576 * 2);
    size_t o_wk    = nxt(1048576 * 2);
    size_t o_wv    = nxt(1048576 * 2);
    size_t o_wo    = nxt(1048576 * 2);
    size_t o_wcond = nxt(524288 * 2);
    size_t o_wout  = nxt(1048576 * 2);
    size_t o_apad  = nxt(256 * 192 * 2);
    size_t o_dp    = nxt(64 * 1024 * 4);
    size_t o_R     = nxt(8 * RB);

    auto WS = [&](size_t o_) { return (ushort_t*)(ws + o_); };
    auto R  = [&](int i)     { return (ushort_t*)(ws + o_R + (size_t)i * RB); };

    auto cvt = [&](const float* src, size_t dst, int n) {
        cvt_kernel<<<dim3(512), dim3(256), 0, stream>>>(src, WS(dst), n / 4);
    };

    // ---- weight conversions ----
    cvt(enc_wv, o_wencv, 1048576);
    cvt(enc_wo, o_wenco, 1048576);
    cvt(conv1_w, o_conv1, 4194304);
    cvt(conv2_w, o_conv2, 4194304);
    cvt(wq, o_wq, 1048576);
    cvt(wk, o_wk, 1048576);
    cvt(wv, o_wv, 1048576);
    cvt(wo, o_wo, 1048576);
    cvt(w_cond, o_wcond, 524288);
    cvt(w_out, o_wout, 1048576);

    // ---- small preps ----
    anorm_kernel<<<dim3(256), dim3(64), 0, stream>>>(wmat, WS(o_apad));
    diffproj_kernel<<<dim3(256), dim3(256), 0, stream>>>(demb, w_diff, b_diff, (float*)(ws + o_dp));
    x1_kernel<<<dim3(3072), dim3(256), 0, stream>>>(x_f, (const float*)(ws + o_dp), R(0));

    // ---- values = x1 @ enc_wv^T + enc_bv  -> R1 ----
    gemm_bt<1><<<dim3(8, 96, 1), 256, 0, stream>>>(R(0), 1024, 0, WS(o_wencv), 1024, 0,
        R(1), 1024, 0, 12288, 1024, enc_bv, nullptr, 0.f, nullptr);
    // ---- transpose values -> valuesT R2 ----
    transp_kernel<<<dim3(32, 6, 64), 256, 0, stream>>>(R(1), R(2));
    // ---- token mix: new_x = A_pad @ valuesT^T (batched) -> R3 ----
    gemm_bt<0><<<dim3(8, 2, 64), 256, 0, stream>>>(WS(o_apad), 192, 0, R(2), 192, 196608LL,
        R(3), 1024, 196608LL, 192, 192, nullptr, nullptr, 0.f, nullptr);
    // ---- s2 = x1 + new_x @ enc_wo^T + enc_bo -> R4 ----
    gemm_bt<3><<<dim3(8, 96, 1), 256, 0, stream>>>(R(3), 1024, 0, WS(o_wenco), 1024, 0,
        R(4), 1024, 0, 12288, 1024, enc_bo, R(0), 0.f, nullptr);
    // ---- x3 = LN(s2, enc_n1) -> R5 ----
    ln_kernel<<<dim3(12288), 256, 0, stream>>>(R(4), en1_g, en1_b, R(5));
    // ---- h = gelu(x3 @ conv1^T + b1) -> R0..R3 (100MB) ----
    gemm_bt<2><<<dim3(32, 96, 1), 256, 0, stream>>>(R(5), 1024, 0, WS(o_conv1), 1024, 0,
        R(0), 4096, 0, 12288, 1024, conv1_b, nullptr, 0.f, nullptr);
    // ---- s6 = x3 + h @ conv2^T + b2 -> R6 ----
    gemm_bt<3><<<dim3(8, 96, 1), 256, 0, stream>>>(R(0), 4096, 0, WS(o_conv2), 4096, 0,
        R(6), 1024, 0, 12288, 4096, conv2_b, R(5), 0.f, nullptr);
    // ---- x5 = LN(LN(s6, enc_n2), ln1) -> R7 ----
    ln2_kernel<<<dim3(12288), 256, 0, stream>>>(R(6), en2_g, en2_b, ln1_g, ln1_b, R(7));
    // ---- q = (x5 @ wq^T) * 0.125 -> R0 ----
    gemm_bt<4><<<dim3(8, 96, 1), 256, 0, stream>>>(R(7), 1024, 0, WS(o_wq), 1024, 0,
        R(0), 1024, 0, 12288, 1024, nullptr, nullptr, 0.125f, nullptr);
    // ---- conds bf16 -> R4 ----
    cvt_kernel<<<dim3(512), dim3(256), 0, stream>>>(conds, R(4), 6291456 / 4);
    // ---- cond = conds @ w_cond^T + b_cond -> R5 ----
    gemm_bt<1><<<dim3(8, 96, 1), 256, 0, stream>>>(R(4), 512, 0, WS(o_wcond), 512, 0,
        R(5), 1024, 0, 12288, 512, b_cond, nullptr, 0.f, nullptr);
    // ---- k -> R1, v -> R2 ----
    gemm_bt<0><<<dim3(8, 96, 1), 256, 0, stream>>>(R(5), 1024, 0, WS(o_wk), 1024, 0,
        R(1), 1024, 0, 12288, 1024, nullptr, nullptr, 0.f, nullptr);
    gemm_bt<0><<<dim3(8, 96, 1), 256, 0, stream>>>(R(5), 1024, 0, WS(o_wv), 1024, 0,
        R(2), 1024, 0, 12288, 1024, nullptr, nullptr, 0.f, nullptr);
    // ---- attention -> o R3 ----
    attn_kernel<<<dim3(3, 16, 64), 256, 0, stream>>>(R(0), R(1), R(2), R(3));
    // ---- xo = o @ wo^T + bo -> R6 ----
    gemm_bt<1><<<dim3(8, 96, 1), 256, 0, stream>>>(R(3), 1024, 0, WS(o_wo), 1024, 0,
        R(6), 1024, 0, 12288, 1024, bo, nullptr, 0.f, nullptr);
    // ---- gated = tanh/sigmoid(LN(xo, ln2)) -> R4 [12288][512] ----
    lngate_kernel<<<dim3(12288), 256, 0, stream>>>(R(6), ln2_g, ln2_b, R(4));
    // ---- final: z = gated @ w_out^T + b_out; leaky; split out/skip -> d_out (f32) ----
    gemm_bt<5><<<dim3(16, 96, 1), 256, 0, stream>>>(R(4), 512, 0, WS(o_wout), 512, 0,
        d_out, 1024, 0, 12288, 512, b_out, nullptr, 0.f, x_f);
}

// Round 2
// 1150.769 us; speedup vs baseline: 1.0325x; 1.0325x over previous
//
#include <hip/hip_runtime.h>

typedef unsigned short ushort_t;
typedef __attribute__((ext_vector_type(8))) short bf16x8;
typedef __attribute__((ext_vector_type(4))) float f32x4;
typedef __attribute__((ext_vector_type(4))) unsigned short u16x4;

#define DEV __device__ __forceinline__

typedef const __attribute__((address_space(1))) void GV;
typedef __attribute__((address_space(3))) void SV;

DEV void gl_lds16(const ushort_t* g, ushort_t* l) {
    __builtin_amdgcn_global_load_lds((GV*)g, (SV*)l, 16, 0, 0);
}

DEV float bf2f(unsigned short u) {
    union { unsigned u; float f; } c; c.u = ((unsigned)u) << 16; return c.f;
}
DEV unsigned short f2bf(float f) {
    union { float f; unsigned u; } c; c.f = f;
    unsigned u = c.u + 0x7fffu + ((c.u >> 16) & 1u);
    return (unsigned short)(u >> 16);
}

DEV f32x4 mfma32(bf16x8 a, bf16x8 b, f32x4 c) {
    return __builtin_amdgcn_mfma_f32_16x16x32_bf16(a, b, c, 0, 0, 0);
}

#define VMCNT4  asm volatile("s_waitcnt vmcnt(4)" ::: "memory")
#define VMCNT8  asm volatile("s_waitcnt vmcnt(8)" ::: "memory")
#define VMCNT10 asm volatile("s_waitcnt vmcnt(10)" ::: "memory")
#define VMCNT0  asm volatile("s_waitcnt vmcnt(0)" ::: "memory")

// ---------------- merged fp32 -> bf16 convert (10 weight segments) ----------------
struct CvtSeg { const float* src; ushort_t* dst; };
struct CvtArgs { CvtSeg s[10]; int cum[11]; };

__global__ void cvt_multi(CvtArgs a, int total4) {
    for (int i = blockIdx.x * 256 + threadIdx.x; i < total4; i += gridDim.x * 256) {
        int seg = 0;
        #pragma unroll
        for (int t = 1; t < 10; t++) if (i >= a.cum[t]) seg = t;
        int off = i - a.cum[seg];
        f32x4 v = *(const f32x4*)(a.s[seg].src + (size_t)off * 4);
        u16x4 o;
        #pragma unroll
        for (int j = 0; j < 4; j++) o[j] = f2bf(v[j]);
        *(u16x4*)(a.s[seg].dst + (size_t)off * 4) = o;
    }
}

// ---------------- generic fp32 -> bf16 convert ----------------
__global__ void cvt_kernel(const float* __restrict__ in, ushort_t* __restrict__ out, int n4) {
    for (int i = blockIdx.x * 256 + threadIdx.x; i < n4; i += gridDim.x * 256) {
        f32x4 v = *(const f32x4*)(in + (size_t)i * 4);
        u16x4 o;
        #pragma unroll
        for (int j = 0; j < 4; j++) o[j] = f2bf(v[j]);
        *(u16x4*)(out + (size_t)i * 4) = o;
    }
}

// ---------------- A_norm: softplus + row-normalize, pad to 256 rows ----------------
__global__ void anorm_kernel(const float* __restrict__ wm, ushort_t* __restrict__ apad) {
    int row = blockIdx.x;           // 0..255
    int lane = threadIdx.x;         // 64 threads
    if (row >= 192) {
        apad[row * 192 + lane] = 0;
        apad[row * 192 + lane + 64] = 0;
        apad[row * 192 + lane + 128] = 0;
        return;
    }
    float x0 = wm[row * 192 + lane];
    float x1 = wm[row * 192 + lane + 64];
    float x2 = wm[row * 192 + lane + 128];
    float s0 = (x0 > 20.f) ? x0 : log1pf(expf(x0));
    float s1 = (x1 > 20.f) ? x1 : log1pf(expf(x1));
    float s2 = (x2 > 20.f) ? x2 : log1pf(expf(x2));
    float t = s0 + s1 + s2;
    #pragma unroll
    for (int m = 1; m < 64; m <<= 1) t += __shfl_xor(t, m);
    float inv = 1.f / t;
    apad[row * 192 + lane]       = f2bf(s0 * inv);
    apad[row * 192 + lane + 64]  = f2bf(s1 * inv);
    apad[row * 192 + lane + 128] = f2bf(s2 * inv);
}

// ---------------- diffproj: diff_emb @ w_diff.T + b_diff (fp32) ----------------
__global__ void diffproj_kernel(const float* __restrict__ emb, const float* __restrict__ w,
                                const float* __restrict__ bias, float* __restrict__ out) {
    int id = blockIdx.x * 256 + threadIdx.x;   // 65536 = 64*1024
    int b = id >> 10, n = id & 1023;
    const float* e = emb + b * 256;
    const float* wr = w + (size_t)n * 256;
    float acc = bias[n];
    for (int k2 = 0; k2 < 256; k2++) acc += e[k2] * wr[k2];
    out[id] = acc;
}

// ---------------- x1 = x + diffproj (broadcast over L), write bf16 ----------------
__global__ void x1_kernel(const float* __restrict__ x, const float* __restrict__ dp,
                          ushort_t* __restrict__ out) {
    const size_t N4 = 12288ULL * 1024 / 4;
    for (size_t i = (size_t)blockIdx.x * 256 + threadIdx.x; i < N4; i += (size_t)gridDim.x * 256) {
        size_t e = i * 4;
        size_t row = e >> 10;
        int d = (int)(e & 1023);
        int bb = (int)(row / 192);
        f32x4 xv = *(const f32x4*)(x + e);
        u16x4 o4;
        #pragma unroll
        for (int j = 0; j < 4; j++) o4[j] = f2bf(xv[j] + dp[bb * 1024 + d + j]);
        *(u16x4*)(out + e) = o4;
    }
}

// ---------------- transpose: values[b][j][d] -> valuesT[b][d][j] (bf16) ----------------
__global__ __launch_bounds__(256) void transp_kernel(const ushort_t* __restrict__ in,
                                                     ushort_t* __restrict__ out) {
    __shared__ ushort_t t[32][33];
    int b = blockIdx.z, jt = blockIdx.y, dt = blockIdx.x;
    int tx = threadIdx.x & 31, ty = threadIdx.x >> 5;
    size_t ib = (size_t)b * 192 * 1024;
    #pragma unroll
    for (int i = 0; i < 4; i++) {
        int j = ty + i * 8;
        t[j][tx] = in[ib + (size_t)(jt * 32 + j) * 1024 + dt * 32 + tx];
    }
    __syncthreads();
    size_t ob = (size_t)b * 1024 * 192;
    #pragma unroll
    for (int i = 0; i < 4; i++) {
        int d = ty + i * 8;
        out[ob + (size_t)(dt * 32 + d) * 192 + jt * 32 + tx] = t[tx][d];
    }
}

// =====================================================================================
// GEMM 256x256 tile, BK=64, 8 waves, 8-phase-style counted-vmcnt pipeline (T1+T2+T3+T4+T5)
// C[M,N] = epi(A[M,K] @ W[N,K]^T)
// EPI: 0 plain->bf16, 1 +bias->bf16, 2 gelu(x+bias)->bf16, 3 +bias+resid->bf16,
//      4 *scale->bf16, 5 final: leaky(x+bias), split out/skip -> f32 d_out
template<int EPI>
__global__ __launch_bounds__(512, 2) void gemm256(
    const ushort_t* __restrict__ A, int lda, long long sAz,
    const ushort_t* __restrict__ W, int ldw, long long sWz,
    void* __restrict__ Cv, int ldc, long long sCz,
    int Mbound, int K,
    const float* __restrict__ bias,
    const ushort_t* __restrict__ resid,
    float scale,
    const float* __restrict__ resf)
{
    __shared__ ushort_t smem[65536];   // 128 KiB: A [2][16384] elems @0, B [2][16384] @32768
    const int tid = threadIdx.x;
    const int wave = tid >> 6, lane = tid & 63, l15 = lane & 15, g = lane >> 4;
    const int wm = wave >> 2, wn = wave & 3;

    // T1: bijective XCD swizzle (grids here always have nwg % 8 == 0)
    int bx = blockIdx.x, by = blockIdx.y;
    if (gridDim.z == 1) {
        int gx = gridDim.x, nwg = gx * gridDim.y;
        if ((nwg & 7) == 0) {
            int orig = by * gx + bx;
            int logi = (orig & 7) * (nwg >> 3) + (orig >> 3);
            bx = logi % gx; by = logi / gx;
        }
    }
    const ushort_t* Ab = A + (size_t)blockIdx.z * sAz + (size_t)by * 256 * lda;
    const ushort_t* Wb = W + (size_t)blockIdx.z * sWz + (size_t)bx * 256 * ldw;

    const int rsub  = lane >> 3;                          // row within 8-row chunk
    const int swsrc = ((lane & 7) ^ (lane >> 3)) * 8;     // pre-swizzled source col (elements)
    const int NT = K >> 6;

    // stage tile kt's 4 half-tiles into buf; per-wave issue order: A0,A0,B0,B0,B1,B1,A1,A1
    auto STAGE = [&](int kt, int buf) {
        const int k0 = kt << 6;
        ushort_t* AL = smem + buf * 16384;
        ushort_t* BL = smem + 32768 + buf * 16384;
        gl_lds16(Ab + (size_t)((wave     ) * 8 + rsub) * lda + k0 + swsrc, AL + (wave     ) * 512);
        gl_lds16(Ab + (size_t)((wave +  8) * 8 + rsub) * lda + k0 + swsrc, AL + (wave +  8) * 512);
        gl_lds16(Wb + (size_t)((wave     ) * 8 + rsub) * ldw + k0 + swsrc, BL + (wave     ) * 512);
        gl_lds16(Wb + (size_t)((wave +  8) * 8 + rsub) * ldw + k0 + swsrc, BL + (wave +  8) * 512);
        gl_lds16(Wb + (size_t)((wave + 16) * 8 + rsub) * ldw + k0 + swsrc, BL + (wave + 16) * 512);
        gl_lds16(Wb + (size_t)((wave + 24) * 8 + rsub) * ldw + k0 + swsrc, BL + (wave + 24) * 512);
        gl_lds16(Ab + (size_t)((wave + 16) * 8 + rsub) * lda + k0 + swsrc, AL + (wave + 16) * 512);
        gl_lds16(Ab + (size_t)((wave + 24) * 8 + rsub) * lda + k0 + swsrc, AL + (wave + 24) * 512);
    };

    auto LDA = [&](bf16x8 (&aa)[4][2], int mh, int buf) {
        const char* base = (const char*)smem + buf * 32768;
        #pragma unroll
        for (int m = 0; m < 4; m++) {
            int r = mh * 128 + wm * 64 + m * 16 + l15;
            #pragma unroll
            for (int kk = 0; kk < 2; kk++) {
                int byo = r * 128 + ((kk * 64 + g * 16) ^ ((l15 & 7) << 4));
                aa[m][kk] = *(const bf16x8*)(base + byo);
            }
        }
    };
    auto LDB = [&](bf16x8 (&bb)[2][2], int nh, int buf) {
        const char* base = (const char*)smem + 65536 + buf * 32768;
        #pragma unroll
        for (int n = 0; n < 2; n++) {
            int r = nh * 128 + wn * 32 + n * 16 + l15;
            #pragma unroll
            for (int kk = 0; kk < 2; kk++) {
                int byo = r * 128 + ((kk * 64 + g * 16) ^ ((l15 & 7) << 4));
                bb[n][kk] = *(const bf16x8*)(base + byo);
            }
        }
    };

    f32x4 acc[2][2][4][2] = {};
    bf16x8 afr[4][2], bfr[2][2];

    auto MM = [&](f32x4 (&aq)[4][2]) {
        __builtin_amdgcn_s_setprio(1);
        #pragma unroll
        for (int m = 0; m < 4; m++)
            #pragma unroll
            for (int n = 0; n < 2; n++)
                #pragma unroll
                for (int kk = 0; kk < 2; kk++)
                    aq[m][n] = mfma32(afr[m][kk], bfr[n][kk], aq[m][n]);
        __builtin_amdgcn_s_setprio(0);
    };

    STAGE(0, 0);   // prologue: tile 0 -> buf 0
    for (int kt = 0; kt < NT; kt++) {
        const int buf = kt & 1;
        const int ktn = (kt + 1 < NT) ? kt + 1 : NT - 1;   // clamp: last tile re-stages (unread)
        // ph1: quadrant (0,0)
        VMCNT4; __builtin_amdgcn_s_barrier();
        LDA(afr, 0, buf); LDB(bfr, 0, buf);
        STAGE(ktn, buf ^ 1);
        MM(acc[0][0]);
        // ph2: quadrant (0,1)
        VMCNT10; __builtin_amdgcn_s_barrier();
        LDB(bfr, 1, buf);
        MM(acc[0][1]);
        // ph3: quadrant (1,1)
        VMCNT8; __builtin_amdgcn_s_barrier();
        LDA(afr, 1, buf);
        MM(acc[1][1]);
        // ph4: quadrant (1,0)  (B0 still resident, no wait needed)
        LDB(bfr, 0, buf);
        MM(acc[1][0]);
    }
    VMCNT0;   // drain redundant last-tile stages before end

    // epilogue
    #pragma unroll
    for (int mh = 0; mh < 2; mh++)
    #pragma unroll
    for (int nh = 0; nh < 2; nh++)
    #pragma unroll
    for (int m = 0; m < 4; m++)
    #pragma unroll
    for (int n = 0; n < 2; n++) {
        int Cc = bx * 256 + nh * 128 + wn * 32 + n * 16 + l15;
        float bval = 0.f;
        if (EPI == 1 || EPI == 2 || EPI == 3 || EPI == 5) bval = bias[Cc];
        #pragma unroll
        for (int q = 0; q < 4; q++) {
            int R = by * 256 + mh * 128 + wm * 64 + m * 16 + g * 4 + q;
            if (R < Mbound) {
                float t = acc[mh][nh][m][n][q];
                if (EPI == 5) {
                    t += bval;
                    t = (t >= 0.f) ? t : 0.4f * t;
                    float* Of = (float*)Cv;
                    if (Cc < 1024)
                        Of[(size_t)R * 1024 + Cc] = (resf[(size_t)R * 1024 + Cc] + t) * 0.70710678118654752f;
                    else
                        Of[12582912ULL + (size_t)R * 1024 + (Cc - 1024)] = t;
                } else {
                    ushort_t* Co = (ushort_t*)Cv + (size_t)blockIdx.z * sCz;
                    if (EPI == 1) t += bval;
                    if (EPI == 2) { t += bval; t = 0.5f * t * (1.f + erff(t * 0.70710678118654752f)); }
                    if (EPI == 3) { t += bval + bf2f(resid[(size_t)R * ldc + Cc]); }
                    if (EPI == 4) { t *= scale; }
                    Co[(size_t)R * ldc + Cc] = f2bf(t);
                }
            }
        }
    }
}

// ---------------- block reduce (256 threads) for LN ----------------
DEV void red2(float& a, float& b) {
    #pragma unroll
    for (int m = 1; m < 64; m <<= 1) { a += __shfl_xor(a, m); b += __shfl_xor(b, m); }
    __shared__ float sa[4], sb[4];
    int w = threadIdx.x >> 6;
    __syncthreads();
    if ((threadIdx.x & 63) == 0) { sa[w] = a; sb[w] = b; }
    __syncthreads();
    a = sa[0] + sa[1] + sa[2] + sa[3];
    b = sb[0] + sb[1] + sb[2] + sb[3];
}

// ---------------- LN (single) ----------------
__global__ __launch_bounds__(256) void ln_kernel(const ushort_t* __restrict__ in,
                                                 const float* __restrict__ gg, const float* __restrict__ bb,
                                                 ushort_t* __restrict__ out) {
    size_t row = blockIdx.x;
    int c0 = threadIdx.x * 4;
    u16x4 r4 = *(const u16x4*)(in + row * 1024 + c0);
    float x[4];
    float s = 0.f, sq = 0.f;
    #pragma unroll
    for (int j = 0; j < 4; j++) { x[j] = bf2f(r4[j]); s += x[j]; sq += x[j] * x[j]; }
    red2(s, sq);
    float m = s * (1.f / 1024.f);
    float var = sq * (1.f / 1024.f) - m * m;
    float rs = rsqrtf(var + 1e-5f);
    u16x4 o4;
    #pragma unroll
    for (int j = 0; j < 4; j++) o4[j] = f2bf((x[j] - m) * rs * gg[c0 + j] + bb[c0 + j]);
    *(u16x4*)(out + row * 1024 + c0) = o4;
}

// ---------------- double LN: ln(ln(x,g1,b1),g2,b2) ----------------
__global__ __launch_bounds__(256) void ln2_kernel(const ushort_t* __restrict__ in,
                                                  const float* __restrict__ g1, const float* __restrict__ b1,
                                                  const float* __restrict__ g2, const float* __restrict__ b2,
                                                  ushort_t* __restrict__ out) {
    size_t row = blockIdx.x;
    int c0 = threadIdx.x * 4;
    u16x4 r4 = *(const u16x4*)(in + row * 1024 + c0);
    float x[4];
    float s = 0.f, sq = 0.f;
    #pragma unroll
    for (int j = 0; j < 4; j++) { x[j] = bf2f(r4[j]); s += x[j]; sq += x[j] * x[j]; }
    red2(s, sq);
    float m = s * (1.f / 1024.f);
    float var = sq * (1.f / 1024.f) - m * m;
    float rs = rsqrtf(var + 1e-5f);
    float t[4];
    float s2 = 0.f, sq2 = 0.f;
    #pragma unroll
    for (int j = 0; j < 4; j++) {
        t[j] = (x[j] - m) * rs * g1[c0 + j] + b1[c0 + j];
        s2 += t[j]; sq2 += t[j] * t[j];
    }
    red2(s2, sq2);
    float m2 = s2 * (1.f / 1024.f);
    float var2 = sq2 * (1.f / 1024.f) - m2 * m2;
    float rs2 = rsqrtf(var2 + 1e-5f);
    u16x4 o4;
    #pragma unroll
    for (int j = 0; j < 4; j++) o4[j] = f2bf((t[j] - m2) * rs2 * g2[c0 + j] + b2[c0 + j]);
    *(u16x4*)(out + row * 1024 + c0) = o4;
}

// ---------------- LN + gate: tanh(g)*sigmoid(f), out [rows][512] bf16 ----------------
__global__ __launch_bounds__(256) void lngate_kernel(const ushort_t* __restrict__ in,
                                                     const float* __restrict__ gg, const float* __restrict__ bb,
                                                     ushort_t* __restrict__ out) {
    __shared__ float buf[1024];
    size_t row = blockIdx.x;
    int c0 = threadIdx.x * 4;
    u16x4 r4 = *(const u16x4*)(in + row * 1024 + c0);
    float x[4];
    float s = 0.f, sq = 0.f;
    #pragma unroll
    for (int j = 0; j < 4; j++) { x[j] = bf2f(r4[j]); s += x[j]; sq += x[j] * x[j]; }
    red2(s, sq);
    float m = s * (1.f / 1024.f);
    float var = sq * (1.f / 1024.f) - m * m;
    float rs = rsqrtf(var + 1e-5f);
    #pragma unroll
    for (int j = 0; j < 4; j++) buf[c0 + j] = (x[j] - m) * rs * gg[c0 + j] + bb[c0 + j];
    __syncthreads();
    if (threadIdx.x < 128) {
        int c = threadIdx.x * 4;
        u16x4 o4;
        #pragma unroll
        for (int j = 0; j < 4; j++) {
            float gv = buf[c + j], fv = buf[c + j + 512];
            o4[j] = f2bf(tanhf(gv) * (1.f / (1.f + expf(-fv))));
        }
        *(u16x4*)(out + row * 512 + c) = o4;
    }
}

// ---------------- attention: per (qtile64, head, batch) block, MFMA QK^T/softmax/PV ----
__global__ __launch_bounds__(256) void attn_kernel(const ushort_t* __restrict__ q,
                                                   const ushort_t* __restrict__ k,
                                                   const ushort_t* __restrict__ v,
                                                   ushort_t* __restrict__ o, int ldkv) {
    __shared__ ushort_t vT[64][208];
    __shared__ ushort_t pS[4][16][208];
    const int tid = threadIdx.x, wave = tid >> 6, lane = tid & 63, l15 = lane & 15, g = lane >> 4;
    const int qb = blockIdx.x, h = blockIdx.y, b = blockIdx.z;
    const size_t baseq = (size_t)b * 192 * 1024 + h * 64;
    const size_t basekv = (size_t)b * 192 * ldkv + h * 64;
    // stage v^T into LDS
    #pragma unroll
    for (int it = 0; it < 6; ++it) {
        int idx = it * 256 + tid;          // 0..1535 : j = idx/8, d8 = (idx%8)*8
        int j = idx >> 3, d8 = (idx & 7) * 8;
        bf16x8 vv = *(const bf16x8*)(v + basekv + (size_t)j * ldkv + d8);
        #pragma unroll
        for (int e = 0; e < 8; e++) vT[d8 + e][j] = (ushort_t)vv[e];
    }
    // QK^T (q is pre-scaled by 1/8)
    const int qrow = qb * 64 + wave * 16 + l15;
    bf16x8 aq[2];
    #pragma unroll
    for (int kk = 0; kk < 2; kk++)
        aq[kk] = *(const bf16x8*)(q + baseq + (size_t)qrow * 1024 + kk * 32 + g * 8);
    f32x4 s[12] = {};
    #pragma unroll
    for (int ni = 0; ni < 12; ni++) {
        #pragma unroll
        for (int kk = 0; kk < 2; kk++) {
            bf16x8 bk = *(const bf16x8*)(k + basekv + (size_t)(ni * 16 + l15) * ldkv + kk * 32 + g * 8);
            s[ni] = mfma32(aq[kk], bk, s[ni]);
        }
    }
    float sminv[4];
    #pragma unroll
    for (int qq = 0; qq < 4; qq++) {
        float m = s[0][qq];
        #pragma unroll
        for (int ni = 1; ni < 12; ni++) m = fmaxf(m, s[ni][qq]);
        #pragma unroll
        for (int msk = 1; msk < 16; msk <<= 1) m = fmaxf(m, __shfl_xor(m, msk));
        float sum = 0.f;
        #pragma unroll
        for (int ni = 0; ni < 12; ni++) {
            float p = expf(s[ni][qq] - m);
            s[ni][qq] = p;
            sum += p;
        }
        #pragma unroll
        for (int msk = 1; msk < 16; msk <<= 1) sum += __shfl_xor(sum, msk);
        sminv[qq] = 1.f / sum;
    }
    #pragma unroll
    for (int ni = 0; ni < 12; ni++)
        #pragma unroll
        for (int qq = 0; qq < 4; qq++)
            pS[wave][g * 4 + qq][ni * 16 + l15] = f2bf(s[ni][qq]);
    __syncthreads();
    f32x4 oa[4] = {};
    #pragma unroll
    for (int ks = 0; ks < 6; ks++) {
        bf16x8 pa = *(const bf16x8*)(&pS[wave][l15][ks * 32 + g * 8]);
        #pragma unroll
        for (int di = 0; di < 4; di++) {
            bf16x8 bv = *(const bf16x8*)(&vT[di * 16 + l15][ks * 32 + g * 8]);
            oa[di] = mfma32(pa, bv, oa[di]);
        }
    }
    #pragma unroll
    for (int di = 0; di < 4; di++)
        #pragma unroll
        for (int qq = 0; qq < 4; qq++) {
            int row = qb * 64 + wave * 16 + g * 4 + qq;
            o[(size_t)b * 192 * 1024 + (size_t)row * 1024 + h * 64 + di * 16 + l15] =
                f2bf(oa[di][qq] * sminv[qq]);
        }
}

// =====================================================================================
extern "C" void kernel_launch(void* const* d_in, const int* in_sizes, int n_in,
                              void* d_out, int out_size, void* d_ws, size_t ws_size,
                              hipStream_t stream) {
    (void)in_sizes; (void)n_in; (void)out_size; (void)ws_size;
    const float* x_f     = (const float*)d_in[0];
    const float* conds   = (const float*)d_in[1];
    const float* demb    = (const float*)d_in[2];
    const float* w_diff  = (const float*)d_in[3];
    const float* b_diff  = (const float*)d_in[4];
    const float* w_cond  = (const float*)d_in[5];
    const float* b_cond  = (const float*)d_in[6];
    const float* wq      = (const float*)d_in[7];
    const float* wk      = (const float*)d_in[8];
    const float* wv      = (const float*)d_in[9];
    const float* wo      = (const float*)d_in[10];
    const float* bo      = (const float*)d_in[11];
    const float* ln1_g   = (const float*)d_in[12];
    const float* ln1_b   = (const float*)d_in[13];
    const float* ln2_g   = (const float*)d_in[14];
    const float* ln2_b   = (const float*)d_in[15];
    const float* w_out   = (const float*)d_in[16];
    const float* b_out   = (const float*)d_in[17];
    const float* enc_wv  = (const float*)d_in[18];
    const float* enc_bv  = (const float*)d_in[19];
    const float* enc_wo  = (const float*)d_in[20];
    const float* enc_bo  = (const float*)d_in[21];
    const float* wmat    = (const float*)d_in[22];
    const float* conv1_w = (const float*)d_in[23];
    const float* conv1_b = (const float*)d_in[24];
    const float* conv2_w = (const float*)d_in[25];
    const float* conv2_b = (const float*)d_in[26];
    const float* en1_g   = (const float*)d_in[27];
    const float* en1_b   = (const float*)d_in[28];
    const float* en2_g   = (const float*)d_in[29];
    const float* en2_b   = (const float*)d_in[30];

    char* ws = (char*)d_ws;
    size_t off = 0;
    auto nxt = [&](size_t b) { size_t r = off; off += (b + 255) & ~(size_t)255; return r; };

    const size_t RB = 12288ULL * 1024 * 2;   // one bf16 region [12288][1024]
    size_t o_wencv = nxt(1048576 * 2);
    size_t o_wenco = nxt(1048576 * 2);
    size_t o_conv1 = nxt(4194304 * 2);
    size_t o_conv2 = nxt(4194304 * 2);
    size_t o_wq    = nxt(1048576 * 2);
    size_t o_wkv   = nxt(2097152 * 2);       // wk then wv stacked: [2048][1024]
    size_t o_wo    = nxt(1048576 * 2);
    size_t o_wcond = nxt(524288 * 2);
    size_t o_wout  = nxt(1048576 * 2);
    size_t o_apad  = nxt(256 * 192 * 2);
    size_t o_dp    = nxt(64 * 1024 * 4);
    size_t o_R     = nxt(8 * RB);

    auto WS = [&](size_t o_) { return (ushort_t*)(ws + o_); };
    auto R  = [&](int i)     { return (ushort_t*)(ws + o_R + (size_t)i * RB); };

    // ---- merged weight conversions (one kernel) ----
    {
        CvtArgs ca;
        const float* srcs[10] = { enc_wv, enc_wo, conv1_w, conv2_w, wq, wk, wv, wo, w_cond, w_out };
        ushort_t*    dsts[10] = { WS(o_wencv), WS(o_wenco), WS(o_conv1), WS(o_conv2), WS(o_wq),
                                  WS(o_wkv), WS(o_wkv) + 1048576, WS(o_wo), WS(o_wcond), WS(o_wout) };
        int          n4s[10]  = { 262144, 262144, 1048576, 1048576, 262144,
                                  262144, 262144, 262144, 131072, 262144 };
        int cum = 0;
        for (int i = 0; i < 10; i++) { ca.s[i].src = srcs[i]; ca.s[i].dst = dsts[i]; ca.cum[i] = cum; cum += n4s[i]; }
        ca.cum[10] = cum;
        cvt_multi<<<dim3(1024), dim3(256), 0, stream>>>(ca, cum);
    }

    // ---- small preps ----
    anorm_kernel<<<dim3(256), dim3(64), 0, stream>>>(wmat, WS(o_apad));
    diffproj_kernel<<<dim3(256), dim3(256), 0, stream>>>(demb, w_diff, b_diff, (float*)(ws + o_dp));
    x1_kernel<<<dim3(3072), dim3(256), 0, stream>>>(x_f, (const float*)(ws + o_dp), R(0));

    // ---- values = x1 @ enc_wv^T + enc_bv  -> R1 ----
    gemm256<1><<<dim3(4, 48, 1), 512, 0, stream>>>(R(0), 1024, 0, WS(o_wencv), 1024, 0,
        R(1), 1024, 0, 12288, 1024, enc_bv, nullptr, 0.f, nullptr);
    // ---- transpose values -> valuesT R2 ----
    transp_kernel<<<dim3(32, 6, 64), 256, 0, stream>>>(R(1), R(2));
    // ---- token mix: new_x = A_pad @ valuesT^T (batched) -> R3 ----
    gemm256<0><<<dim3(4, 1, 64), 512, 0, stream>>>(WS(o_apad), 192, 0, R(2), 192, 196608LL,
        R(3), 1024, 196608LL, 192, 192, nullptr, nullptr, 0.f, nullptr);
    // ---- s2 = x1 + new_x @ enc_wo^T + enc_bo -> R4 ----
    gemm256<3><<<dim3(4, 48, 1), 512, 0, stream>>>(R(3), 1024, 0, WS(o_wenco), 1024, 0,
        R(4), 1024, 0, 12288, 1024, enc_bo, R(0), 0.f, nullptr);
    // ---- x3 = LN(s2, enc_n1) -> R5 ----
    ln_kernel<<<dim3(12288), 256, 0, stream>>>(R(4), en1_g, en1_b, R(5));
    // ---- h = gelu(x3 @ conv1^T + b1) -> R0..R3 (100MB) ----
    gemm256<2><<<dim3(16, 48, 1), 512, 0, stream>>>(R(5), 1024, 0, WS(o_conv1), 1024, 0,
        R(0), 4096, 0, 12288, 1024, conv1_b, nullptr, 0.f, nullptr);
    // ---- s6 = x3 + h @ conv2^T + b2 -> R6 ----
    gemm256<3><<<dim3(4, 48, 1), 512, 0, stream>>>(R(0), 4096, 0, WS(o_conv2), 4096, 0,
        R(6), 1024, 0, 12288, 4096, conv2_b, R(5), 0.f, nullptr);
    // ---- x5 = LN(LN(s6, enc_n2), ln1) -> R7 ----
    ln2_kernel<<<dim3(12288), 256, 0, stream>>>(R(6), en2_g, en2_b, ln1_g, ln1_b, R(7));
    // ---- q = (x5 @ wq^T) * 0.125 -> R0 ----
    gemm256<4><<<dim3(4, 48, 1), 512, 0, stream>>>(R(7), 1024, 0, WS(o_wq), 1024, 0,
        R(0), 1024, 0, 12288, 1024, nullptr, nullptr, 0.125f, nullptr);
    // ---- conds bf16 -> R4 (free after ln) ----
    cvt_kernel<<<dim3(512), dim3(256), 0, stream>>>(conds, R(4), 6291456 / 4);
    // ---- cond = conds @ w_cond^T + b_cond -> R5 ----
    gemm256<1><<<dim3(4, 48, 1), 512, 0, stream>>>(R(4), 512, 0, WS(o_wcond), 512, 0,
        R(5), 1024, 0, 12288, 512, b_cond, nullptr, 0.f, nullptr);
    // ---- k,v merged: cond @ [wk;wv]^T -> C [12288][2048] spanning R1,R2 ----
    gemm256<0><<<dim3(8, 48, 1), 512, 0, stream>>>(R(5), 1024, 0, WS(o_wkv), 1024, 0,
        R(1), 2048, 0, 12288, 1024, nullptr, nullptr, 0.f, nullptr);
    // ---- attention -> o R3 ----
    attn_kernel<<<dim3(3, 16, 64), 256, 0, stream>>>(R(0), R(1), R(1) + 1024, R(3), 2048);
    // ---- xo = o @ wo^T + bo -> R6 ----
    gemm256<1><<<dim3(4, 48, 1), 512, 0, stream>>>(R(3), 1024, 0, WS(o_wo), 1024, 0,
        R(6), 1024, 0, 12288, 1024, bo, nullptr, 0.f, nullptr);
    // ---- gated = tanh/sigmoid(LN(xo, ln2)) -> R4 [12288][512] ----
    lngate_kernel<<<dim3(12288), 256, 0, stream>>>(R(6), ln2_g, ln2_b, R(4));
    // ---- final: z = gated @ w_out^T + b_out; leaky; split out/skip -> d_out (f32) ----
    gemm256<5><<<dim3(8, 48, 1), 512, 0, stream>>>(R(4), 512, 0, WS(o_wout), 512, 0,
        d_out, 1024, 0, 12288, 512, b_out, nullptr, 0.f, x_f);
}

// Round 3
// 1128.594 us; speedup vs baseline: 1.0528x; 1.0196x over previous
//
#include <hip/hip_runtime.h>

typedef unsigned short ushort_t;
typedef __attribute__((ext_vector_type(8))) short bf16x8;
typedef __attribute__((ext_vector_type(4))) float f32x4;
typedef __attribute__((ext_vector_type(4))) unsigned short u16x4;

#define DEV __device__ __forceinline__

typedef const __attribute__((address_space(1))) void GV;
typedef __attribute__((address_space(3))) void SV;

DEV void gl_lds16(const ushort_t* g, ushort_t* l) {
    __builtin_amdgcn_global_load_lds((GV*)g, (SV*)l, 16, 0, 0);
}

DEV float bf2f(unsigned short u) {
    union { unsigned u; float f; } c; c.u = ((unsigned)u) << 16; return c.f;
}
DEV unsigned short f2bf(float f) {
    union { float f; unsigned u; } c; c.f = f;
    unsigned u = c.u + 0x7fffu + ((c.u >> 16) & 1u);
    return (unsigned short)(u >> 16);
}

DEV f32x4 mfma32(bf16x8 a, bf16x8 b, f32x4 c) {
    return __builtin_amdgcn_mfma_f32_16x16x32_bf16(a, b, c, 0, 0, 0);
}

#define VMCNT6  asm volatile("s_waitcnt vmcnt(6)" ::: "memory")
#define VMCNT0  asm volatile("s_waitcnt vmcnt(0)" ::: "memory")
#define LGKM0   asm volatile("s_waitcnt lgkmcnt(0)" ::: "memory")
#define SCHEDB  __builtin_amdgcn_sched_barrier(0)
#define BAR     __builtin_amdgcn_s_barrier()

// ---------------- merged fp32 -> bf16 convert (10 weight segments) ----------------
struct CvtSeg { const float* src; ushort_t* dst; };
struct CvtArgs { CvtSeg s[10]; int cum[11]; };

__global__ void cvt_multi(CvtArgs a, int total4) {
    for (int i = blockIdx.x * 256 + threadIdx.x; i < total4; i += gridDim.x * 256) {
        int seg = 0;
        #pragma unroll
        for (int t = 1; t < 10; t++) if (i >= a.cum[t]) seg = t;
        int off = i - a.cum[seg];
        f32x4 v = *(const f32x4*)(a.s[seg].src + (size_t)off * 4);
        u16x4 o;
        #pragma unroll
        for (int j = 0; j < 4; j++) o[j] = f2bf(v[j]);
        *(u16x4*)(a.s[seg].dst + (size_t)off * 4) = o;
    }
}

// ---------------- generic fp32 -> bf16 convert ----------------
__global__ void cvt_kernel(const float* __restrict__ in, ushort_t* __restrict__ out, int n4) {
    for (int i = blockIdx.x * 256 + threadIdx.x; i < n4; i += gridDim.x * 256) {
        f32x4 v = *(const f32x4*)(in + (size_t)i * 4);
        u16x4 o;
        #pragma unroll
        for (int j = 0; j < 4; j++) o[j] = f2bf(v[j]);
        *(u16x4*)(out + (size_t)i * 4) = o;
    }
}

// ---------------- A_norm: softplus + row-normalize, pad to 256 rows ----------------
__global__ void anorm_kernel(const float* __restrict__ wm, ushort_t* __restrict__ apad) {
    int row = blockIdx.x;           // 0..255
    int lane = threadIdx.x;         // 64 threads
    if (row >= 192) {
        apad[row * 192 + lane] = 0;
        apad[row * 192 + lane + 64] = 0;
        apad[row * 192 + lane + 128] = 0;
        return;
    }
    float x0 = wm[row * 192 + lane];
    float x1 = wm[row * 192 + lane + 64];
    float x2 = wm[row * 192 + lane + 128];
    float s0 = (x0 > 20.f) ? x0 : log1pf(expf(x0));
    float s1 = (x1 > 20.f) ? x1 : log1pf(expf(x1));
    float s2 = (x2 > 20.f) ? x2 : log1pf(expf(x2));
    float t = s0 + s1 + s2;
    #pragma unroll
    for (int m = 1; m < 64; m <<= 1) t += __shfl_xor(t, m);
    float inv = 1.f / t;
    apad[row * 192 + lane]       = f2bf(s0 * inv);
    apad[row * 192 + lane + 64]  = f2bf(s1 * inv);
    apad[row * 192 + lane + 128] = f2bf(s2 * inv);
}

// ---------------- diffproj: diff_emb @ w_diff.T + b_diff (fp32) ----------------
__global__ void diffproj_kernel(const float* __restrict__ emb, const float* __restrict__ w,
                                const float* __restrict__ bias, float* __restrict__ out) {
    int id = blockIdx.x * 256 + threadIdx.x;   // 65536 = 64*1024
    int b = id >> 10, n = id & 1023;
    const float* e = emb + b * 256;
    const float* wr = w + (size_t)n * 256;
    float acc = bias[n];
    for (int k2 = 0; k2 < 256; k2++) acc += e[k2] * wr[k2];
    out[id] = acc;
}

// ---------------- x1 = x + diffproj (broadcast over L), write bf16 ----------------
__global__ void x1_kernel(const float* __restrict__ x, const float* __restrict__ dp,
                          ushort_t* __restrict__ out) {
    const size_t N4 = 12288ULL * 1024 / 4;
    for (size_t i = (size_t)blockIdx.x * 256 + threadIdx.x; i < N4; i += (size_t)gridDim.x * 256) {
        size_t e = i * 4;
        size_t row = e >> 10;
        int d = (int)(e & 1023);
        int bb = (int)(row / 192);
        f32x4 xv = *(const f32x4*)(x + e);
        u16x4 o4;
        #pragma unroll
        for (int j = 0; j < 4; j++) o4[j] = f2bf(xv[j] + dp[bb * 1024 + d + j]);
        *(u16x4*)(out + e) = o4;
    }
}

// ---------------- transpose: values[b][j][d] -> valuesT[b][d][j] (bf16) ----------------
__global__ __launch_bounds__(256) void transp_kernel(const ushort_t* __restrict__ in,
                                                     ushort_t* __restrict__ out) {
    __shared__ ushort_t t[32][33];
    int b = blockIdx.z, jt = blockIdx.y, dt = blockIdx.x;
    int tx = threadIdx.x & 31, ty = threadIdx.x >> 5;
    size_t ib = (size_t)b * 192 * 1024;
    #pragma unroll
    for (int i = 0; i < 4; i++) {
        int j = ty + i * 8;
        t[j][tx] = in[ib + (size_t)(jt * 32 + j) * 1024 + dt * 32 + tx];
    }
    __syncthreads();
    size_t ob = (size_t)b * 1024 * 192;
    #pragma unroll
    for (int i = 0; i < 4; i++) {
        int d = ty + i * 8;
        out[ob + (size_t)(dt * 32 + d) * 192 + jt * 32 + tx] = t[tx][d];
    }
}

// =====================================================================================
// GEMM 256x256 tile, BK=64, 8 waves (2Mx4N), m201 8-phase schedule (T1+T2+T3+T4+T5).
// Per K-tile: 4 phases = C-quadrants (0,0),(0,1),(1,1),(1,0); each phase:
//   {ds_read subtile | stage ONE half-tile (2 gl_lds)} -> barrier -> lgkmcnt(0) ->
//   setprio(1) 16xMFMA setprio(0) -> barrier.
// vmcnt(6) once per tile (ph4): tile t+1 fully landed; 3 half-tiles (t+2) in flight.
// In-tile stage order Alo,Bhi,Ahi,Blo matches each slot's last-read phase.
// C[M,N] = epi(A[M,K] @ W[N,K]^T)
template<int EPI>
__global__ __launch_bounds__(512, 2) void gemm256(
    const ushort_t* __restrict__ A, int lda, long long sAz,
    const ushort_t* __restrict__ W, int ldw, long long sWz,
    void* __restrict__ Cv, int ldc, long long sCz,
    int Mbound, int K,
    const float* __restrict__ bias,
    const ushort_t* __restrict__ resid,
    float scale,
    const float* __restrict__ resf)
{
    __shared__ ushort_t smem[65536];   // A: [buf][half] 4x8192 @0 ; B: @32768
    const int tid = threadIdx.x;
    const int wave = tid >> 6, lane = tid & 63, l15 = lane & 15, g = lane >> 4;
    const int wm = wave >> 2, wn = wave & 3;

    // T1: bijective XCD swizzle (2D grids here always have nwg % 8 == 0)
    int bx = blockIdx.x, by = blockIdx.y;
    if (gridDim.z == 1) {
        int gx = gridDim.x, nwg = gx * gridDim.y;
        if ((nwg & 7) == 0) {
            int orig = by * gx + bx;
            int logi = (orig & 7) * (nwg >> 3) + (orig >> 3);
            bx = logi % gx; by = logi / gx;
        }
    }
    const ushort_t* Ab = A + (size_t)blockIdx.z * sAz + (size_t)by * 256 * lda;
    const ushort_t* Wb = W + (size_t)blockIdx.z * sWz + (size_t)bx * 256 * ldw;

    const int chunkr = lane >> 3;                       // row within 8-row chunk
    const int swsrc  = ((lane & 7) ^ chunkr) * 8;       // pre-swizzled source col (elems)
    const int NT = K >> 6;

    // stage one half-tile: 2 gl_lds per wave (chunks wave*2, wave*2+1; 8 rows each)
    auto SH_A = [&](int tile, int half, int buf) {
        const ushort_t* src = Ab + (size_t)(half * 128) * lda + (tile << 6) + swsrc;
        ushort_t* dst = smem + (buf * 2 + half) * 8192;
        int c = wave * 2;
        gl_lds16(src + (size_t)(c * 8 + chunkr) * lda,       dst + c * 512);
        gl_lds16(src + (size_t)((c + 1) * 8 + chunkr) * lda, dst + (c + 1) * 512);
    };
    auto SH_B = [&](int tile, int half, int buf) {
        const ushort_t* src = Wb + (size_t)(half * 128) * ldw + (tile << 6) + swsrc;
        ushort_t* dst = smem + 32768 + (buf * 2 + half) * 8192;
        int c = wave * 2;
        gl_lds16(src + (size_t)(c * 8 + chunkr) * ldw,       dst + c * 512);
        gl_lds16(src + (size_t)((c + 1) * 8 + chunkr) * ldw, dst + (c + 1) * 512);
    };

    auto LDA_ = [&](bf16x8 (&aa)[4][2], int half, int buf) {
        const char* base = (const char*)(smem + (buf * 2 + half) * 8192);
        #pragma unroll
        for (int m = 0; m < 4; m++) {
            int r = wm * 64 + m * 16 + l15;
            #pragma unroll
            for (int kk = 0; kk < 2; kk++)
                aa[m][kk] = *(const bf16x8*)(base + r * 128 + ((kk * 64 + g * 16) ^ ((l15 & 7) << 4)));
        }
    };
    auto LDB_ = [&](bf16x8 (&bb)[2][2], int half, int buf) {
        const char* base = (const char*)(smem + 32768 + (buf * 2 + half) * 8192);
        #pragma unroll
        for (int n = 0; n < 2; n++) {
            int r = wn * 32 + n * 16 + l15;
            #pragma unroll
            for (int kk = 0; kk < 2; kk++)
                bb[n][kk] = *(const bf16x8*)(base + r * 128 + ((kk * 64 + g * 16) ^ ((l15 & 7) << 4)));
        }
    };

    f32x4 acc[2][2][4][2] = {};
    bf16x8 afr[4][2], blo[2][2], bhi[2][2];

    auto MM = [&](f32x4 (&aq)[4][2], bf16x8 (&bb)[2][2]) {
        #pragma unroll
        for (int m = 0; m < 4; m++)
            #pragma unroll
            for (int n = 0; n < 2; n++)
                #pragma unroll
                for (int kk = 0; kk < 2; kk++)
                    aq[m][n] = mfma32(afr[m][kk], bb[n][kk], aq[m][n]);
    };

    // ---- prologue: tile0 (Alo,Bhi,Ahi,Blo) + tile1 (Alo,Bhi,Ahi); tile0 landed ----
    SH_A(0, 0, 0); SH_B(0, 1, 0); SH_A(0, 1, 0); SH_B(0, 0, 0);
    {
        int t1 = (NT > 1) ? 1 : 0;
        SH_A(t1, 0, 1); SH_B(t1, 1, 1); SH_A(t1, 1, 1);
    }
    VMCNT6;
    BAR;

    for (int t = 0; t < NT; t++) {
        const int b = t & 1, nb = b ^ 1;
        const int t1 = (t + 1 < NT) ? t + 1 : NT - 1;
        const int t2 = (t + 2 < NT) ? t + 2 : NT - 1;
        // ph1: quadrant (0,0); stage Blo(t+1)
        LDA_(afr, 0, b); LDB_(blo, 0, b);
        SH_B(t1, 0, nb);
        BAR; LGKM0; SCHEDB;
        __builtin_amdgcn_s_setprio(1); MM(acc[0][0], blo); __builtin_amdgcn_s_setprio(0);
        BAR;
        // ph2: quadrant (0,1); stage Alo(t+2)
        LDB_(bhi, 1, b);
        SH_A(t2, 0, b);
        BAR; LGKM0; SCHEDB;
        __builtin_amdgcn_s_setprio(1); MM(acc[0][1], bhi); __builtin_amdgcn_s_setprio(0);
        BAR;
        // ph3: quadrant (1,1); stage Bhi(t+2)
        LDA_(afr, 1, b);
        SH_B(t2, 1, b);
        BAR; LGKM0; SCHEDB;
        __builtin_amdgcn_s_setprio(1); MM(acc[1][1], bhi); __builtin_amdgcn_s_setprio(0);
        BAR;
        // ph4: quadrant (1,0); stage Ahi(t+2); B-lo frags held in regs
        SH_A(t2, 1, b);
        VMCNT6;
        BAR; SCHEDB;
        __builtin_amdgcn_s_setprio(1); MM(acc[1][0], blo); __builtin_amdgcn_s_setprio(0);
        BAR;
    }
    VMCNT0;   // drain redundant clamped stages

    // epilogue
    #pragma unroll
    for (int mh = 0; mh < 2; mh++)
    #pragma unroll
    for (int nh = 0; nh < 2; nh++)
    #pragma unroll
    for (int m = 0; m < 4; m++)
    #pragma unroll
    for (int n = 0; n < 2; n++) {
        int Cc = bx * 256 + nh * 128 + wn * 32 + n * 16 + l15;
        float bval = 0.f;
        if (EPI == 1 || EPI == 2 || EPI == 3 || EPI == 5) bval = bias[Cc];
        #pragma unroll
        for (int q = 0; q < 4; q++) {
            int R = by * 256 + mh * 128 + wm * 64 + m * 16 + g * 4 + q;
            if (R < Mbound) {
                float t = acc[mh][nh][m][n][q];
                if (EPI == 5) {
                    t += bval;
                    t = (t >= 0.f) ? t : 0.4f * t;
                    float* Of = (float*)Cv;
                    if (Cc < 1024)
                        Of[(size_t)R * 1024 + Cc] = (resf[(size_t)R * 1024 + Cc] + t) * 0.70710678118654752f;
                    else
                        Of[12582912ULL + (size_t)R * 1024 + (Cc - 1024)] = t;
                } else {
                    ushort_t* Co = (ushort_t*)Cv + (size_t)blockIdx.z * sCz;
                    if (EPI == 1) t += bval;
                    if (EPI == 2) { t += bval; t = 0.5f * t * (1.f + erff(t * 0.70710678118654752f)); }
                    if (EPI == 3) { t += bval + bf2f(resid[(size_t)R * ldc + Cc]); }
                    if (EPI == 4) { t *= scale; }
                    Co[(size_t)R * ldc + Cc] = f2bf(t);
                }
            }
        }
    }
}

// ---------------- block reduce (256 threads) for LN ----------------
DEV void red2(float& a, float& b) {
    #pragma unroll
    for (int m = 1; m < 64; m <<= 1) { a += __shfl_xor(a, m); b += __shfl_xor(b, m); }
    __shared__ float sa[4], sb[4];
    int w = threadIdx.x >> 6;
    __syncthreads();
    if ((threadIdx.x & 63) == 0) { sa[w] = a; sb[w] = b; }
    __syncthreads();
    a = sa[0] + sa[1] + sa[2] + sa[3];
    b = sb[0] + sb[1] + sb[2] + sb[3];
}

// ---------------- LN (single) ----------------
__global__ __launch_bounds__(256) void ln_kernel(const ushort_t* __restrict__ in,
                                                 const float* __restrict__ gg, const float* __restrict__ bb,
                                                 ushort_t* __restrict__ out) {
    size_t row = blockIdx.x;
    int c0 = threadIdx.x * 4;
    u16x4 r4 = *(const u16x4*)(in + row * 1024 + c0);
    float x[4];
    float s = 0.f, sq = 0.f;
    #pragma unroll
    for (int j = 0; j < 4; j++) { x[j] = bf2f(r4[j]); s += x[j]; sq += x[j] * x[j]; }
    red2(s, sq);
    float m = s * (1.f / 1024.f);
    float var = sq * (1.f / 1024.f) - m * m;
    float rs = rsqrtf(var + 1e-5f);
    u16x4 o4;
    #pragma unroll
    for (int j = 0; j < 4; j++) o4[j] = f2bf((x[j] - m) * rs * gg[c0 + j] + bb[c0 + j]);
    *(u16x4*)(out + row * 1024 + c0) = o4;
}

// ---------------- double LN: ln(ln(x,g1,b1),g2,b2) ----------------
__global__ __launch_bounds__(256) void ln2_kernel(const ushort_t* __restrict__ in,
                                                  const float* __restrict__ g1, const float* __restrict__ b1,
                                                  const float* __restrict__ g2, const float* __restrict__ b2,
                                                  ushort_t* __restrict__ out) {
    size_t row = blockIdx.x;
    int c0 = threadIdx.x * 4;
    u16x4 r4 = *(const u16x4*)(in + row * 1024 + c0);
    float x[4];
    float s = 0.f, sq = 0.f;
    #pragma unroll
    for (int j = 0; j < 4; j++) { x[j] = bf2f(r4[j]); s += x[j]; sq += x[j] * x[j]; }
    red2(s, sq);
    float m = s * (1.f / 1024.f);
    float var = sq * (1.f / 1024.f) - m * m;
    float rs = rsqrtf(var + 1e-5f);
    float t[4];
    float s2 = 0.f, sq2 = 0.f;
    #pragma unroll
    for (int j = 0; j < 4; j++) {
        t[j] = (x[j] - m) * rs * g1[c0 + j] + b1[c0 + j];
        s2 += t[j]; sq2 += t[j] * t[j];
    }
    red2(s2, sq2);
    float m2 = s2 * (1.f / 1024.f);
    float var2 = sq2 * (1.f / 1024.f) - m2 * m2;
    float rs2 = rsqrtf(var2 + 1e-5f);
    u16x4 o4;
    #pragma unroll
    for (int j = 0; j < 4; j++) o4[j] = f2bf((t[j] - m2) * rs2 * g2[c0 + j] + b2[c0 + j]);
    *(u16x4*)(out + row * 1024 + c0) = o4;
}

// ---------------- LN + gate: tanh(g)*sigmoid(f), out [rows][512] bf16 ----------------
__global__ __launch_bounds__(256) void lngate_kernel(const ushort_t* __restrict__ in,
                                                     const float* __restrict__ gg, const float* __restrict__ bb,
                                                     ushort_t* __restrict__ out) {
    __shared__ float buf[1024];
    size_t row = blockIdx.x;
    int c0 = threadIdx.x * 4;
    u16x4 r4 = *(const u16x4*)(in + row * 1024 + c0);
    float x[4];
    float s = 0.f, sq = 0.f;
    #pragma unroll
    for (int j = 0; j < 4; j++) { x[j] = bf2f(r4[j]); s += x[j]; sq += x[j] * x[j]; }
    red2(s, sq);
    float m = s * (1.f / 1024.f);
    float var = sq * (1.f / 1024.f) - m * m;
    float rs = rsqrtf(var + 1e-5f);
    #pragma unroll
    for (int j = 0; j < 4; j++) buf[c0 + j] = (x[j] - m) * rs * gg[c0 + j] + bb[c0 + j];
    __syncthreads();
    if (threadIdx.x < 128) {
        int c = threadIdx.x * 4;
        u16x4 o4;
        #pragma unroll
        for (int j = 0; j < 4; j++) {
            float gv = buf[c + j], fv = buf[c + j + 512];
            o4[j] = f2bf(tanhf(gv) * (1.f / (1.f + expf(-fv))));
        }
        *(u16x4*)(out + row * 512 + c) = o4;
    }
}

// ---------------- attention: per (qtile64, head, batch) block, MFMA QK^T/softmax/PV ----
__global__ __launch_bounds__(256) void attn_kernel(const ushort_t* __restrict__ q,
                                                   const ushort_t* __restrict__ k,
                                                   const ushort_t* __restrict__ v,
                                                   ushort_t* __restrict__ o, int ldkv) {
    __shared__ ushort_t vT[64][208];
    __shared__ ushort_t pS[4][16][208];
    const int tid = threadIdx.x, wave = tid >> 6, lane = tid & 63, l15 = lane & 15, g = lane >> 4;
    const int qb = blockIdx.x, h = blockIdx.y, b = blockIdx.z;
    const size_t baseq = (size_t)b * 192 * 1024 + h * 64;
    const size_t basekv = (size_t)b * 192 * ldkv + h * 64;
    #pragma unroll
    for (int it = 0; it < 6; ++it) {
        int idx = it * 256 + tid;
        int j = idx >> 3, d8 = (idx & 7) * 8;
        bf16x8 vv = *(const bf16x8*)(v + basekv + (size_t)j * ldkv + d8);
        #pragma unroll
        for (int e = 0; e < 8; e++) vT[d8 + e][j] = (ushort_t)vv[e];
    }
    const int qrow = qb * 64 + wave * 16 + l15;
    bf16x8 aq[2];
    #pragma unroll
    for (int kk = 0; kk < 2; kk++)
        aq[kk] = *(const bf16x8*)(q + baseq + (size_t)qrow * 1024 + kk * 32 + g * 8);
    f32x4 s[12] = {};
    #pragma unroll
    for (int ni = 0; ni < 12; ni++) {
        #pragma unroll
        for (int kk = 0; kk < 2; kk++) {
            bf16x8 bk = *(const bf16x8*)(k + basekv + (size_t)(ni * 16 + l15) * ldkv + kk * 32 + g * 8);
            s[ni] = mfma32(aq[kk], bk, s[ni]);
        }
    }
    float sminv[4];
    #pragma unroll
    for (int qq = 0; qq < 4; qq++) {
        float m = s[0][qq];
        #pragma unroll
        for (int ni = 1; ni < 12; ni++) m = fmaxf(m, s[ni][qq]);
        #pragma unroll
        for (int msk = 1; msk < 16; msk <<= 1) m = fmaxf(m, __shfl_xor(m, msk));
        float sum = 0.f;
        #pragma unroll
        for (int ni = 0; ni < 12; ni++) {
            float p = expf(s[ni][qq] - m);
            s[ni][qq] = p;
            sum += p;
        }
        #pragma unroll
        for (int msk = 1; msk < 16; msk <<= 1) sum += __shfl_xor(sum, msk);
        sminv[qq] = 1.f / sum;
    }
    #pragma unroll
    for (int ni = 0; ni < 12; ni++)
        #pragma unroll
        for (int qq = 0; qq < 4; qq++)
            pS[wave][g * 4 + qq][ni * 16 + l15] = f2bf(s[ni][qq]);
    __syncthreads();
    f32x4 oa[4] = {};
    #pragma unroll
    for (int ks = 0; ks < 6; ks++) {
        bf16x8 pa = *(const bf16x8*)(&pS[wave][l15][ks * 32 + g * 8]);
        #pragma unroll
        for (int di = 0; di < 4; di++) {
            bf16x8 bv = *(const bf16x8*)(&vT[di * 16 + l15][ks * 32 + g * 8]);
            oa[di] = mfma32(pa, bv, oa[di]);
        }
    }
    #pragma unroll
    for (int di = 0; di < 4; di++)
        #pragma unroll
        for (int qq = 0; qq < 4; qq++) {
            int row = qb * 64 + wave * 16 + g * 4 + qq;
            o[(size_t)b * 192 * 1024 + (size_t)row * 1024 + h * 64 + di * 16 + l15] =
                f2bf(oa[di][qq] * sminv[qq]);
        }
}

// =====================================================================================
extern "C" void kernel_launch(void* const* d_in, const int* in_sizes, int n_in,
                              void* d_out, int out_size, void* d_ws, size_t ws_size,
                              hipStream_t stream) {
    (void)in_sizes; (void)n_in; (void)out_size; (void)ws_size;
    const float* x_f     = (const float*)d_in[0];
    const float* conds   = (const float*)d_in[1];
    const float* demb    = (const float*)d_in[2];
    const float* w_diff  = (const float*)d_in[3];
    const float* b_diff  = (const float*)d_in[4];
    const float* w_cond  = (const float*)d_in[5];
    const float* b_cond  = (const float*)d_in[6];
    const float* wq      = (const float*)d_in[7];
    const float* wk      = (const float*)d_in[8];
    const float* wv      = (const float*)d_in[9];
    const float* wo      = (const float*)d_in[10];
    const float* bo      = (const float*)d_in[11];
    const float* ln1_g   = (const float*)d_in[12];
    const float* ln1_b   = (const float*)d_in[13];
    const float* ln2_g   = (const float*)d_in[14];
    const float* ln2_b   = (const float*)d_in[15];
    const float* w_out   = (const float*)d_in[16];
    const float* b_out   = (const float*)d_in[17];
    const float* enc_wv  = (const float*)d_in[18];
    const float* enc_bv  = (const float*)d_in[19];
    const float* enc_wo  = (const float*)d_in[20];
    const float* enc_bo  = (const float*)d_in[21];
    const float* wmat    = (const float*)d_in[22];
    const float* conv1_w = (const float*)d_in[23];
    const float* conv1_b = (const float*)d_in[24];
    const float* conv2_w = (const float*)d_in[25];
    const float* conv2_b = (const float*)d_in[26];
    const float* en1_g   = (const float*)d_in[27];
    const float* en1_b   = (const float*)d_in[28];
    const float* en2_g   = (const float*)d_in[29];
    const float* en2_b   = (const float*)d_in[30];

    char* ws = (char*)d_ws;
    size_t off = 0;
    auto nxt = [&](size_t b) { size_t r = off; off += (b + 255) & ~(size_t)255; return r; };

    const size_t RB = 12288ULL * 1024 * 2;   // one bf16 region [12288][1024]
    size_t o_wencv = nxt(1048576 * 2);
    size_t o_wenco = nxt(1048576 * 2);
    size_t o_conv1 = nxt(4194304 * 2);
    size_t o_conv2 = nxt(4194304 * 2);
    size_t o_wq    = nxt(1048576 * 2);
    size_t o_wkv   = nxt(2097152 * 2);       // wk then wv stacked: [2048][1024]
    size_t o_wo    = nxt(1048576 * 2);
    size_t o_wcond = nxt(524288 * 2);
    size_t o_wout  = nxt(1048576 * 2);
    size_t o_apad  = nxt(256 * 192 * 2);
    size_t o_dp    = nxt(64 * 1024 * 4);
    size_t o_R     = nxt(8 * RB);

    auto WS = [&](size_t o_) { return (ushort_t*)(ws + o_); };
    auto R  = [&](int i)     { return (ushort_t*)(ws + o_R + (size_t)i * RB); };

    // ---- merged weight conversions (one kernel) ----
    {
        CvtArgs ca;
        const float* srcs[10] = { enc_wv, enc_wo, conv1_w, conv2_w, wq, wk, wv, wo, w_cond, w_out };
        ushort_t*    dsts[10] = { WS(o_wencv), WS(o_wenco), WS(o_conv1), WS(o_conv2), WS(o_wq),
                                  WS(o_wkv), WS(o_wkv) + 1048576, WS(o_wo), WS(o_wcond), WS(o_wout) };
        int          n4s[10]  = { 262144, 262144, 1048576, 1048576, 262144,
                                  262144, 262144, 262144, 131072, 262144 };
        int cum = 0;
        for (int i = 0; i < 10; i++) { ca.s[i].src = srcs[i]; ca.s[i].dst = dsts[i]; ca.cum[i] = cum; cum += n4s[i]; }
        ca.cum[10] = cum;
        cvt_multi<<<dim3(1024), dim3(256), 0, stream>>>(ca, cum);
    }

    // ---- small preps ----
    anorm_kernel<<<dim3(256), dim3(64), 0, stream>>>(wmat, WS(o_apad));
    diffproj_kernel<<<dim3(256), dim3(256), 0, stream>>>(demb, w_diff, b_diff, (float*)(ws + o_dp));
    x1_kernel<<<dim3(3072), dim3(256), 0, stream>>>(x_f, (const float*)(ws + o_dp), R(0));

    // ---- values = x1 @ enc_wv^T + enc_bv  -> R1 ----
    gemm256<1><<<dim3(4, 48, 1), 512, 0, stream>>>(R(0), 1024, 0, WS(o_wencv), 1024, 0,
        R(1), 1024, 0, 12288, 1024, enc_bv, nullptr, 0.f, nullptr);
    // ---- transpose values -> valuesT R2 ----
    transp_kernel<<<dim3(32, 6, 64), 256, 0, stream>>>(R(1), R(2));
    // ---- token mix: new_x = A_pad @ valuesT^T (batched) -> R3 ----
    gemm256<0><<<dim3(4, 1, 64), 512, 0, stream>>>(WS(o_apad), 192, 0, R(2), 192, 196608LL,
        R(3), 1024, 196608LL, 192, 192, nullptr, nullptr, 0.f, nullptr);
    // ---- s2 = x1 + new_x @ enc_wo^T + enc_bo -> R4 ----
    gemm256<3><<<dim3(4, 48, 1), 512, 0, stream>>>(R(3), 1024, 0, WS(o_wenco), 1024, 0,
        R(4), 1024, 0, 12288, 1024, enc_bo, R(0), 0.f, nullptr);
    // ---- x3 = LN(s2, enc_n1) -> R5 ----
    ln_kernel<<<dim3(12288), 256, 0, stream>>>(R(4), en1_g, en1_b, R(5));
    // ---- h = gelu(x3 @ conv1^T + b1) -> R0..R3 (100MB) ----
    gemm256<2><<<dim3(16, 48, 1), 512, 0, stream>>>(R(5), 1024, 0, WS(o_conv1), 1024, 0,
        R(0), 4096, 0, 12288, 1024, conv1_b, nullptr, 0.f, nullptr);
    // ---- s6 = x3 + h @ conv2^T + b2 -> R6 ----
    gemm256<3><<<dim3(4, 48, 1), 512, 0, stream>>>(R(0), 4096, 0, WS(o_conv2), 4096, 0,
        R(6), 1024, 0, 12288, 4096, conv2_b, R(5), 0.f, nullptr);
    // ---- x5 = LN(LN(s6, enc_n2), ln1) -> R7 ----
    ln2_kernel<<<dim3(12288), 256, 0, stream>>>(R(6), en2_g, en2_b, ln1_g, ln1_b, R(7));
    // ---- q = (x5 @ wq^T) * 0.125 -> R0 ----
    gemm256<4><<<dim3(4, 48, 1), 512, 0, stream>>>(R(7), 1024, 0, WS(o_wq), 1024, 0,
        R(0), 1024, 0, 12288, 1024, nullptr, nullptr, 0.125f, nullptr);
    // ---- conds bf16 -> R4 (free after ln) ----
    cvt_kernel<<<dim3(512), dim3(256), 0, stream>>>(conds, R(4), 6291456 / 4);
    // ---- cond = conds @ w_cond^T + b_cond -> R5 ----
    gemm256<1><<<dim3(4, 48, 1), 512, 0, stream>>>(R(4), 512, 0, WS(o_wcond), 512, 0,
        R(5), 1024, 0, 12288, 512, b_cond, nullptr, 0.f, nullptr);
    // ---- k,v merged: cond @ [wk;wv]^T -> C [12288][2048] spanning R1,R2 ----
    gemm256<0><<<dim3(8, 48, 1), 512, 0, stream>>>(R(5), 1024, 0, WS(o_wkv), 1024, 0,
        R(1), 2048, 0, 12288, 1024, nullptr, nullptr, 0.f, nullptr);
    // ---- attention -> o R3 ----
    attn_kernel<<<dim3(3, 16, 64), 256, 0, stream>>>(R(0), R(1), R(1) + 1024, R(3), 2048);
    // ---- xo = o @ wo^T + bo -> R6 ----
    gemm256<1><<<dim3(4, 48, 1), 512, 0, stream>>>(R(3), 1024, 0, WS(o_wo), 1024, 0,
        R(6), 1024, 0, 12288, 1024, bo, nullptr, 0.f, nullptr);
    // ---- gated = tanh/sigmoid(LN(xo, ln2)) -> R4 [12288][512] ----
    lngate_kernel<<<dim3(12288), 256, 0, stream>>>(R(6), ln2_g, ln2_b, R(4));
    // ---- final: z = gated @ w_out^T + b_out; leaky; split out/skip -> d_out (f32) ----
    gemm256<5><<<dim3(8, 48, 1), 512, 0, stream>>>(R(4), 512, 0, WS(o_wout), 512, 0,
        d_out, 1024, 0, 12288, 512, b_out, nullptr, 0.f, x_f);
}

// Round 6
// 1102.306 us; speedup vs baseline: 1.0779x; 1.0238x over previous
//
#include <hip/hip_runtime.h>

typedef unsigned short ushort_t;
typedef __attribute__((ext_vector_type(8))) short bf16x8;
typedef __attribute__((ext_vector_type(4))) float f32x4;
typedef __attribute__((ext_vector_type(4))) unsigned short u16x4;

#define DEV __device__ __forceinline__

typedef const __attribute__((address_space(1))) void GV;
typedef __attribute__((address_space(3))) void SV;

DEV void gl_lds16(const ushort_t* g, ushort_t* l) {
    __builtin_amdgcn_global_load_lds((GV*)g, (SV*)l, 16, 0, 0);
}

DEV float bf2f(unsigned short u) {
    union { unsigned u; float f; } c; c.u = ((unsigned)u) << 16; return c.f;
}
DEV unsigned short f2bf(float f) {
    union { float f; unsigned u; } c; c.f = f;
    unsigned u = c.u + 0x7fffu + ((c.u >> 16) & 1u);
    return (unsigned short)(u >> 16);
}

DEV f32x4 mfma32(bf16x8 a, bf16x8 b, f32x4 c) {
    return __builtin_amdgcn_mfma_f32_16x16x32_bf16(a, b, c, 0, 0, 0);
}

#define VMCNT6  asm volatile("s_waitcnt vmcnt(6)" ::: "memory")
#define VMCNT0  asm volatile("s_waitcnt vmcnt(0)" ::: "memory")
#define LGKM0   asm volatile("s_waitcnt lgkmcnt(0)" ::: "memory")
#define BAR     __builtin_amdgcn_s_barrier()

// ---------------- merged fp32 -> bf16 convert (10 weight segments) ----------------
struct CvtSeg { const float* src; ushort_t* dst; };
struct CvtArgs { CvtSeg s[10]; int cum[11]; };

__global__ void cvt_multi(CvtArgs a, int total4) {
    for (int i = blockIdx.x * 256 + threadIdx.x; i < total4; i += gridDim.x * 256) {
        int seg = 0;
        #pragma unroll
        for (int t = 1; t < 10; t++) if (i >= a.cum[t]) seg = t;
        int off = i - a.cum[seg];
        f32x4 v = *(const f32x4*)(a.s[seg].src + (size_t)off * 4);
        u16x4 o;
        #pragma unroll
        for (int j = 0; j < 4; j++) o[j] = f2bf(v[j]);
        *(u16x4*)(a.s[seg].dst + (size_t)off * 4) = o;
    }
}

// ---------------- generic fp32 -> bf16 convert ----------------
__global__ void cvt_kernel(const float* __restrict__ in, ushort_t* __restrict__ out, int n4) {
    for (int i = blockIdx.x * 256 + threadIdx.x; i < n4; i += gridDim.x * 256) {
        f32x4 v = *(const f32x4*)(in + (size_t)i * 4);
        u16x4 o;
        #pragma unroll
        for (int j = 0; j < 4; j++) o[j] = f2bf(v[j]);
        *(u16x4*)(out + (size_t)i * 4) = o;
    }
}

// ---------------- A_norm: softplus + row-normalize, pad to 256 rows ----------------
__global__ void anorm_kernel(const float* __restrict__ wm, ushort_t* __restrict__ apad) {
    int row = blockIdx.x;           // 0..255
    int lane = threadIdx.x;         // 64 threads
    if (row >= 192) {
        apad[row * 192 + lane] = 0;
        apad[row * 192 + lane + 64] = 0;
        apad[row * 192 + lane + 128] = 0;
        return;
    }
    float x0 = wm[row * 192 + lane];
    float x1 = wm[row * 192 + lane + 64];
    float x2 = wm[row * 192 + lane + 128];
    float s0 = (x0 > 20.f) ? x0 : log1pf(expf(x0));
    float s1 = (x1 > 20.f) ? x1 : log1pf(expf(x1));
    float s2 = (x2 > 20.f) ? x2 : log1pf(expf(x2));
    float t = s0 + s1 + s2;
    #pragma unroll
    for (int m = 1; m < 64; m <<= 1) t += __shfl_xor(t, m);
    float inv = 1.f / t;
    apad[row * 192 + lane]       = f2bf(s0 * inv);
    apad[row * 192 + lane + 64]  = f2bf(s1 * inv);
    apad[row * 192 + lane + 128] = f2bf(s2 * inv);
}

// ---------------- diffproj: diff_emb @ w_diff.T + b_diff (fp32) ----------------
__global__ void diffproj_kernel(const float* __restrict__ emb, const float* __restrict__ w,
                                const float* __restrict__ bias, float* __restrict__ out) {
    int id = blockIdx.x * 256 + threadIdx.x;   // 65536 = 64*1024
    int b = id >> 10, n = id & 1023;
    const float* e = emb + b * 256;
    const float* wr = w + (size_t)n * 256;
    float acc = bias[n];
    for (int k2 = 0; k2 < 256; k2++) acc += e[k2] * wr[k2];
    out[id] = acc;
}

// ---------------- x1 = x + diffproj (broadcast over L), write bf16 ----------------
__global__ void x1_kernel(const float* __restrict__ x, const float* __restrict__ dp,
                          ushort_t* __restrict__ out) {
    const size_t N4 = 12288ULL * 1024 / 4;
    for (size_t i = (size_t)blockIdx.x * 256 + threadIdx.x; i < N4; i += (size_t)gridDim.x * 256) {
        size_t e = i * 4;
        size_t row = e >> 10;
        int d = (int)(e & 1023);
        int bb = (int)(row / 192);
        f32x4 xv = *(const f32x4*)(x + e);
        u16x4 o4;
        #pragma unroll
        for (int j = 0; j < 4; j++) o4[j] = f2bf(xv[j] + dp[bb * 1024 + d + j]);
        *(u16x4*)(out + e) = o4;
    }
}

// ---------------- transpose: values[b][j][d] -> valuesT[b][d][j] (bf16) ----------------
__global__ __launch_bounds__(256) void transp_kernel(const ushort_t* __restrict__ in,
                                                     ushort_t* __restrict__ out) {
    __shared__ ushort_t t[32][33];
    int b = blockIdx.z, jt = blockIdx.y, dt = blockIdx.x;
    int tx = threadIdx.x & 31, ty = threadIdx.x >> 5;
    size_t ib = (size_t)b * 192 * 1024;
    #pragma unroll
    for (int i = 0; i < 4; i++) {
        int j = ty + i * 8;
        t[j][tx] = in[ib + (size_t)(jt * 32 + j) * 1024 + dt * 32 + tx];
    }
    __syncthreads();
    size_t ob = (size_t)b * 1024 * 192;
    #pragma unroll
    for (int i = 0; i < 4; i++) {
        int d = ty + i * 8;
        out[ob + (size_t)(dt * 32 + d) * 192 + jt * 32 + tx] = t[tx][d];
    }
}

// =====================================================================================
// GEMM 256x256 tile, BK=64, 8 waves (2Mx4N). Register-pipelined quadrant schedule:
// quadrants (0,0),(0,1),(1,1),(1,0); fragment ds_reads issued one phase ahead so LDS
// service overlaps the previous quadrant's MFMAs (compiler emits counted lgkm waits).
// A0 for tile t+1 prefetched at ph4 after VMCNT6+BAR (next-tile LDS guaranteed landed).
// Stage order per tile: ph1 Blo(t+1), ph2 Alo(t+2), ph3 Bhi(t+2), ph4 Ahi(t+2);
// vmcnt(6) at ph4 = drain to newest 3 stages (t+2's). C[M,N] = epi(A[M,K] @ W[N,K]^T).
template<int EPI>
__global__ __launch_bounds__(512, 2) void gemm256(
    const ushort_t* __restrict__ A, int lda, long long sAz,
    const ushort_t* __restrict__ W, int ldw, long long sWz,
    void* __restrict__ Cv, int ldc, long long sCz,
    int Mbound, int K,
    const float* __restrict__ bias,
    const ushort_t* __restrict__ resid,
    float scale,
    const float* __restrict__ resf)
{
    __shared__ ushort_t smem[65536];   // A: [buf][half] 4x8192 @0 ; B: @32768
    const int tid = threadIdx.x;
    const int wave = tid >> 6, lane = tid & 63, l15 = lane & 15, g = lane >> 4;
    const int wm = wave >> 2, wn = wave & 3;

    // T1: bijective XCD swizzle (2D grids here always have nwg % 8 == 0)
    int bx = blockIdx.x, by = blockIdx.y;
    if (gridDim.z == 1) {
        int gx = gridDim.x, nwg = gx * gridDim.y;
        if ((nwg & 7) == 0) {
            int orig = by * gx + bx;
            int logi = (orig & 7) * (nwg >> 3) + (orig >> 3);
            bx = logi % gx; by = logi / gx;
        }
    }
    const ushort_t* Ab = A + (size_t)blockIdx.z * sAz + (size_t)by * 256 * lda;
    const ushort_t* Wb = W + (size_t)blockIdx.z * sWz + (size_t)bx * 256 * ldw;

    const int chunkr = lane >> 3;                       // row within 8-row chunk
    const int swsrc  = ((lane & 7) ^ chunkr) * 8;       // pre-swizzled source col (elems)
    const int NT = K >> 6;

    // stage one half-tile: 2 gl_lds per wave (chunks wave*2, wave*2+1; 8 rows each)
    auto SH_A = [&](int tile, int half, int buf) {
        const ushort_t* src = Ab + (size_t)(half * 128) * lda + (tile << 6) + swsrc;
        ushort_t* dst = smem + (buf * 2 + half) * 8192;
        int c = wave * 2;
        gl_lds16(src + (size_t)(c * 8 + chunkr) * lda,       dst + c * 512);
        gl_lds16(src + (size_t)((c + 1) * 8 + chunkr) * lda, dst + (c + 1) * 512);
    };
    auto SH_B = [&](int tile, int half, int buf) {
        const ushort_t* src = Wb + (size_t)(half * 128) * ldw + (tile << 6) + swsrc;
        ushort_t* dst = smem + 32768 + (buf * 2 + half) * 8192;
        int c = wave * 2;
        gl_lds16(src + (size_t)(c * 8 + chunkr) * ldw,       dst + c * 512);
        gl_lds16(src + (size_t)((c + 1) * 8 + chunkr) * ldw, dst + (c + 1) * 512);
    };

    auto LDA_ = [&](bf16x8 (&aa)[4][2], int half, int buf) {
        const char* base = (const char*)(smem + (buf * 2 + half) * 8192);
        #pragma unroll
        for (int m = 0; m < 4; m++) {
            int r = wm * 64 + m * 16 + l15;
            #pragma unroll
            for (int kk = 0; kk < 2; kk++)
                aa[m][kk] = *(const bf16x8*)(base + r * 128 + ((kk * 64 + g * 16) ^ ((l15 & 7) << 4)));
        }
    };
    auto LDB_ = [&](bf16x8 (&bb)[2][2], int half, int buf) {
        const char* base = (const char*)(smem + 32768 + (buf * 2 + half) * 8192);
        #pragma unroll
        for (int n = 0; n < 2; n++) {
            int r = wn * 32 + n * 16 + l15;
            #pragma unroll
            for (int kk = 0; kk < 2; kk++)
                bb[n][kk] = *(const bf16x8*)(base + r * 128 + ((kk * 64 + g * 16) ^ ((l15 & 7) << 4)));
        }
    };

    f32x4 acc[2][2][4][2] = {};
    bf16x8 a0[4][2], a1[4][2], b0[2][2], b1[2][2];

    auto MMQ = [&](f32x4 (&aq)[4][2], bf16x8 (&aa)[4][2], bf16x8 (&bb)[2][2]) {
        __builtin_amdgcn_s_setprio(1);
        #pragma unroll
        for (int m = 0; m < 4; m++)
            #pragma unroll
            for (int n = 0; n < 2; n++)
                #pragma unroll
                for (int kk = 0; kk < 2; kk++)
                    aq[m][n] = mfma32(aa[m][kk], bb[n][kk], aq[m][n]);
        __builtin_amdgcn_s_setprio(0);
    };

    // ---- prologue: tile0 (Alo,Bhi,Ahi,Blo) + tile1 (Alo,Bhi,Ahi); tile0 landed ----
    SH_A(0, 0, 0); SH_B(0, 1, 0); SH_A(0, 1, 0); SH_B(0, 0, 0);
    {
        int t1 = (NT > 1) ? 1 : 0;
        SH_A(t1, 0, 1); SH_B(t1, 1, 1); SH_A(t1, 1, 1);
    }
    VMCNT6;
    BAR;
    LDA_(a0, 0, 0);    // prefetch A-lo frags of tile 0

    for (int t = 0; t < NT; t++) {
        const int b = t & 1, nb = b ^ 1;
        const int t1 = (t + 1 < NT) ? t + 1 : NT - 1;
        const int t2 = (t + 2 < NT) ? t + 2 : NT - 1;
        // ph1: q(0,0)=a0*b0. issue b0,b1 reads; stage Blo(t+1). (b0 wait exposed ~latency)
        LDB_(b0, 0, b); LDB_(b1, 1, b);
        SH_B(t1, 0, nb);
        MMQ(acc[0][0], a0, b0);
        BAR;
        // ph2: q(0,1)=a0*b1 (b1 issued ph1, hidden). issue a1 reads; stage Alo(t+2).
        LDA_(a1, 1, b);
        SH_A(t2, 0, b);
        MMQ(acc[0][1], a0, b1);
        BAR;
        // ph3: q(1,1)=a1*b1 (a1 issued ph2, hidden). stage Bhi(t+2).
        SH_B(t2, 1, b);
        MMQ(acc[1][1], a1, b1);
        BAR;
        // ph4: q(1,0)=a1*b0 (no wait). stage Ahi(t+2); vmcnt(6)+BAR: tile t+1 landed;
        //      prefetch a0 of tile t+1 from nb (overlaps this quadrant's MFMAs).
        SH_A(t2, 1, b);
        VMCNT6;
        BAR;
        LDA_(a0, 0, nb);
        MMQ(acc[1][0], a1, b0);
        BAR;
    }
    VMCNT0;
    LGKM0;

    // epilogue
    #pragma unroll
    for (int mh = 0; mh < 2; mh++)
    #pragma unroll
    for (int nh = 0; nh < 2; nh++)
    #pragma unroll
    for (int m = 0; m < 4; m++)
    #pragma unroll
    for (int n = 0; n < 2; n++) {
        int Cc = bx * 256 + nh * 128 + wn * 32 + n * 16 + l15;
        float bval = 0.f;
        if (EPI == 1 || EPI == 2 || EPI == 3 || EPI == 5) bval = bias[Cc];
        #pragma unroll
        for (int q = 0; q < 4; q++) {
            int R = by * 256 + mh * 128 + wm * 64 + m * 16 + g * 4 + q;
            if (R < Mbound) {
                float t = acc[mh][nh][m][n][q];
                if (EPI == 5) {
                    t += bval;
                    t = (t >= 0.f) ? t : 0.4f * t;
                    float* Of = (float*)Cv;
                    if (Cc < 1024)
                        Of[(size_t)R * 1024 + Cc] = (resf[(size_t)R * 1024 + Cc] + t) * 0.70710678118654752f;
                    else
                        Of[12582912ULL + (size_t)R * 1024 + (Cc - 1024)] = t;
                } else {
                    ushort_t* Co = (ushort_t*)Cv + (size_t)blockIdx.z * sCz;
                    if (EPI == 1) t += bval;
                    if (EPI == 2) { t += bval; t = 0.5f * t * (1.f + erff(t * 0.70710678118654752f)); }
                    if (EPI == 3) { t += bval + bf2f(resid[(size_t)R * ldc + Cc]); }
                    if (EPI == 4) { t *= scale; }
                    Co[(size_t)R * ldc + Cc] = f2bf(t);
                }
            }
        }
    }
}

// ---------------- block reduce (256 threads) for LN ----------------
DEV void red2(float& a, float& b) {
    #pragma unroll
    for (int m = 1; m < 64; m <<= 1) { a += __shfl_xor(a, m); b += __shfl_xor(b, m); }
    __shared__ float sa[4], sb[4];
    int w = threadIdx.x >> 6;
    __syncthreads();
    if ((threadIdx.x & 63) == 0) { sa[w] = a; sb[w] = b; }
    __syncthreads();
    a = sa[0] + sa[1] + sa[2] + sa[3];
    b = sb[0] + sb[1] + sb[2] + sb[3];
}

// ---------------- LN (single) ----------------
__global__ __launch_bounds__(256) void ln_kernel(const ushort_t* __restrict__ in,
                                                 const float* __restrict__ gg, const float* __restrict__ bb,
                                                 ushort_t* __restrict__ out) {
    size_t row = blockIdx.x;
    int c0 = threadIdx.x * 4;
    u16x4 r4 = *(const u16x4*)(in + row * 1024 + c0);
    float x[4];
    float s = 0.f, sq = 0.f;
    #pragma unroll
    for (int j = 0; j < 4; j++) { x[j] = bf2f(r4[j]); s += x[j]; sq += x[j] * x[j]; }
    red2(s, sq);
    float m = s * (1.f / 1024.f);
    float var = sq * (1.f / 1024.f) - m * m;
    float rs = rsqrtf(var + 1e-5f);
    u16x4 o4;
    #pragma unroll
    for (int j = 0; j < 4; j++) o4[j] = f2bf((x[j] - m) * rs * gg[c0 + j] + bb[c0 + j]);
    *(u16x4*)(out + row * 1024 + c0) = o4;
}

// ---------------- double LN: ln(ln(x,g1,b1),g2,b2) ----------------
__global__ __launch_bounds__(256) void ln2_kernel(const ushort_t* __restrict__ in,
                                                  const float* __restrict__ g1, const float* __restrict__ b1,
                                                  const float* __restrict__ g2, const float* __restrict__ b2,
                                                  ushort_t* __restrict__ out) {
    size_t row = blockIdx.x;
    int c0 = threadIdx.x * 4;
    u16x4 r4 = *(const u16x4*)(in + row * 1024 + c0);
    float x[4];
    float s = 0.f, sq = 0.f;
    #pragma unroll
    for (int j = 0; j < 4; j++) { x[j] = bf2f(r4[j]); s += x[j]; sq += x[j] * x[j]; }
    red2(s, sq);
    float m = s * (1.f / 1024.f);
    float var = sq * (1.f / 1024.f) - m * m;
    float rs = rsqrtf(var + 1e-5f);
    float t[4];
    float s2 = 0.f, sq2 = 0.f;
    #pragma unroll
    for (int j = 0; j < 4; j++) {
        t[j] = (x[j] - m) * rs * g1[c0 + j] + b1[c0 + j];
        s2 += t[j]; sq2 += t[j] * t[j];
    }
    red2(s2, sq2);
    float m2 = s2 * (1.f / 1024.f);
    float var2 = sq2 * (1.f / 1024.f) - m2 * m2;
    float rs2 = rsqrtf(var2 + 1e-5f);
    u16x4 o4;
    #pragma unroll
    for (int j = 0; j < 4; j++) o4[j] = f2bf((t[j] - m2) * rs2 * g2[c0 + j] + b2[c0 + j]);
    *(u16x4*)(out + row * 1024 + c0) = o4;
}

// ---------------- LN + gate: tanh(g)*sigmoid(f), out [rows][512] bf16 ----------------
__global__ __launch_bounds__(256) void lngate_kernel(const ushort_t* __restrict__ in,
                                                     const float* __restrict__ gg, const float* __restrict__ bb,
                                                     ushort_t* __restrict__ out) {
    __shared__ float buf[1024];
    size_t row = blockIdx.x;
    int c0 = threadIdx.x * 4;
    u16x4 r4 = *(const u16x4*)(in + row * 1024 + c0);
    float x[4];
    float s = 0.f, sq = 0.f;
    #pragma unroll
    for (int j = 0; j < 4; j++) { x[j] = bf2f(r4[j]); s += x[j]; sq += x[j] * x[j]; }
    red2(s, sq);
    float m = s * (1.f / 1024.f);
    float var = sq * (1.f / 1024.f) - m * m;
    float rs = rsqrtf(var + 1e-5f);
    #pragma unroll
    for (int j = 0; j < 4; j++) buf[c0 + j] = (x[j] - m) * rs * gg[c0 + j] + bb[c0 + j];
    __syncthreads();
    if (threadIdx.x < 128) {
        int c = threadIdx.x * 4;
        u16x4 o4;
        #pragma unroll
        for (int j = 0; j < 4; j++) {
            float gv = buf[c + j], fv = buf[c + j + 512];
            o4[j] = f2bf(tanhf(gv) * (1.f / (1.f + expf(-fv))));
        }
        *(u16x4*)(out + row * 512 + c) = o4;
    }
}

// ---------------- attention: per (qtile64, head, batch) block, MFMA QK^T/softmax/PV ----
__global__ __launch_bounds__(256) void attn_kernel(const ushort_t* __restrict__ q,
                                                   const ushort_t* __restrict__ k,
                                                   const ushort_t* __restrict__ v,
                                                   ushort_t* __restrict__ o, int ldkv) {
    __shared__ ushort_t vT[64][208];
    __shared__ ushort_t pS[4][16][208];
    const int tid = threadIdx.x, wave = tid >> 6, lane = tid & 63, l15 = lane & 15, g = lane >> 4;
    const int qb = blockIdx.x, h = blockIdx.y, b = blockIdx.z;
    const size_t baseq = (size_t)b * 192 * 1024 + h * 64;
    const size_t basekv = (size_t)b * 192 * ldkv + h * 64;
    #pragma unroll
    for (int it = 0; it < 6; ++it) {
        int idx = it * 256 + tid;
        int j = idx >> 3, d8 = (idx & 7) * 8;
        bf16x8 vv = *(const bf16x8*)(v + basekv + (size_t)j * ldkv + d8);
        #pragma unroll
        for (int e = 0; e < 8; e++) vT[d8 + e][j] = (ushort_t)vv[e];
    }
    const int qrow = qb * 64 + wave * 16 + l15;
    bf16x8 aq[2];
    #pragma unroll
    for (int kk = 0; kk < 2; kk++)
        aq[kk] = *(const bf16x8*)(q + baseq + (size_t)qrow * 1024 + kk * 32 + g * 8);
    f32x4 s[12] = {};
    #pragma unroll
    for (int ni = 0; ni < 12; ni++) {
        #pragma unroll
        for (int kk = 0; kk < 2; kk++) {
            bf16x8 bk = *(const bf16x8*)(k + basekv + (size_t)(ni * 16 + l15) * ldkv + kk * 32 + g * 8);
            s[ni] = mfma32(aq[kk], bk, s[ni]);
        }
    }
    float sminv[4];
    #pragma unroll
    for (int qq = 0; qq < 4; qq++) {
        float m = s[0][qq];
        #pragma unroll
        for (int ni = 1; ni < 12; ni++) m = fmaxf(m, s[ni][qq]);
        #pragma unroll
        for (int msk = 1; msk < 16; msk <<= 1) m = fmaxf(m, __shfl_xor(m, msk));
        float sum = 0.f;
        #pragma unroll
        for (int ni = 0; ni < 12; ni++) {
            float p = expf(s[ni][qq] - m);
            s[ni][qq] = p;
            sum += p;
        }
        #pragma unroll
        for (int msk = 1; msk < 16; msk <<= 1) sum += __shfl_xor(sum, msk);
        sminv[qq] = 1.f / sum;
    }
    #pragma unroll
    for (int ni = 0; ni < 12; ni++)
        #pragma unroll
        for (int qq = 0; qq < 4; qq++)
            pS[wave][g * 4 + qq][ni * 16 + l15] = f2bf(s[ni][qq]);
    __syncthreads();
    f32x4 oa[4] = {};
    #pragma unroll
    for (int ks = 0; ks < 6; ks++) {
        bf16x8 pa = *(const bf16x8*)(&pS[wave][l15][ks * 32 + g * 8]);
        #pragma unroll
        for (int di = 0; di < 4; di++) {
            bf16x8 bv = *(const bf16x8*)(&vT[di * 16 + l15][ks * 32 + g * 8]);
            oa[di] = mfma32(pa, bv, oa[di]);
        }
    }
    #pragma unroll
    for (int di = 0; di < 4; di++)
        #pragma unroll
        for (int qq = 0; qq < 4; qq++) {
            int row = qb * 64 + wave * 16 + g * 4 + qq;
            o[(size_t)b * 192 * 1024 + (size_t)row * 1024 + h * 64 + di * 16 + l15] =
                f2bf(oa[di][qq] * sminv[qq]);
        }
}

// =====================================================================================
extern "C" void kernel_launch(void* const* d_in, const int* in_sizes, int n_in,
                              void* d_out, int out_size, void* d_ws, size_t ws_size,
                              hipStream_t stream) {
    (void)in_sizes; (void)n_in; (void)out_size; (void)ws_size;
    const float* x_f     = (const float*)d_in[0];
    const float* conds   = (const float*)d_in[1];
    const float* demb    = (const float*)d_in[2];
    const float* w_diff  = (const float*)d_in[3];
    const float* b_diff  = (const float*)d_in[4];
    const float* w_cond  = (const float*)d_in[5];
    const float* b_cond  = (const float*)d_in[6];
    const float* wq      = (const float*)d_in[7];
    const float* wk      = (const float*)d_in[8];
    const float* wv      = (const float*)d_in[9];
    const float* wo      = (const float*)d_in[10];
    const float* bo      = (const float*)d_in[11];
    const float* ln1_g   = (const float*)d_in[12];
    const float* ln1_b   = (const float*)d_in[13];
    const float* ln2_g   = (const float*)d_in[14];
    const float* ln2_b   = (const float*)d_in[15];
    const float* w_out   = (const float*)d_in[16];
    const float* b_out   = (const float*)d_in[17];
    const float* enc_wv  = (const float*)d_in[18];
    const float* enc_bv  = (const float*)d_in[19];
    const float* enc_wo  = (const float*)d_in[20];
    const float* enc_bo  = (const float*)d_in[21];
    const float* wmat    = (const float*)d_in[22];
    const float* conv1_w = (const float*)d_in[23];
    const float* conv1_b = (const float*)d_in[24];
    const float* conv2_w = (const float*)d_in[25];
    const float* conv2_b = (const float*)d_in[26];
    const float* en1_g   = (const float*)d_in[27];
    const float* en1_b   = (const float*)d_in[28];
    const float* en2_g   = (const float*)d_in[29];
    const float* en2_b   = (const float*)d_in[30];

    char* ws = (char*)d_ws;
    size_t off = 0;
    auto nxt = [&](size_t b) { size_t r = off; off += (b + 255) & ~(size_t)255; return r; };

    const size_t RB = 12288ULL * 1024 * 2;   // one bf16 region [12288][1024]
    size_t o_wencv = nxt(1048576 * 2);
    size_t o_wenco = nxt(1048576 * 2);
    size_t o_conv1 = nxt(4194304 * 2);
    size_t o_conv2 = nxt(4194304 * 2);
    size_t o_wq    = nxt(1048576 * 2);
    size_t o_wkv   = nxt(2097152 * 2);       // wk then wv stacked: [2048][1024]
    size_t o_wo    = nxt(1048576 * 2);
    size_t o_wcond = nxt(524288 * 2);
    size_t o_wout  = nxt(1048576 * 2);
    size_t o_apad  = nxt(256 * 192 * 2);
    size_t o_dp    = nxt(64 * 1024 * 4);
    size_t o_R     = nxt(8 * RB);

    auto WS = [&](size_t o_) { return (ushort_t*)(ws + o_); };
    auto R  = [&](int i)     { return (ushort_t*)(ws + o_R + (size_t)i * RB); };

    // ---- merged weight conversions (one kernel) ----
    {
        CvtArgs ca;
        const float* srcs[10] = { enc_wv, enc_wo, conv1_w, conv2_w, wq, wk, wv, wo, w_cond, w_out };
        ushort_t*    dsts[10] = { WS(o_wencv), WS(o_wenco), WS(o_conv1), WS(o_conv2), WS(o_wq),
                                  WS(o_wkv), WS(o_wkv) + 1048576, WS(o_wo), WS(o_wcond), WS(o_wout) };
        int          n4s[10]  = { 262144, 262144, 1048576, 1048576, 262144,
                                  262144, 262144, 262144, 131072, 262144 };
        int cum = 0;
        for (int i = 0; i < 10; i++) { ca.s[i].src = srcs[i]; ca.s[i].dst = dsts[i]; ca.cum[i] = cum; cum += n4s[i]; }
        ca.cum[10] = cum;
        cvt_multi<<<dim3(1024), dim3(256), 0, stream>>>(ca, cum);
    }

    // ---- small preps ----
    anorm_kernel<<<dim3(256), dim3(64), 0, stream>>>(wmat, WS(o_apad));
    diffproj_kernel<<<dim3(256), dim3(256), 0, stream>>>(demb, w_diff, b_diff, (float*)(ws + o_dp));
    x1_kernel<<<dim3(3072), dim3(256), 0, stream>>>(x_f, (const float*)(ws + o_dp), R(0));

    // ---- values = x1 @ enc_wv^T + enc_bv  -> R1 ----
    gemm256<1><<<dim3(4, 48, 1), 512, 0, stream>>>(R(0), 1024, 0, WS(o_wencv), 1024, 0,
        R(1), 1024, 0, 12288, 1024, enc_bv, nullptr, 0.f, nullptr);
    // ---- transpose values -> valuesT R2 ----
    transp_kernel<<<dim3(32, 6, 64), 256, 0, stream>>>(R(1), R(2));
    // ---- token mix: new_x = A_pad @ valuesT^T (batched) -> R3 ----
    gemm256<0><<<dim3(4, 1, 64), 512, 0, stream>>>(WS(o_apad), 192, 0, R(2), 192, 196608LL,
        R(3), 1024, 196608LL, 192, 192, nullptr, nullptr, 0.f, nullptr);
    // ---- s2 = x1 + new_x @ enc_wo^T + enc_bo -> R4 ----
    gemm256<3><<<dim3(4, 48, 1), 512, 0, stream>>>(R(3), 1024, 0, WS(o_wenco), 1024, 0,
        R(4), 1024, 0, 12288, 1024, enc_bo, R(0), 0.f, nullptr);
    // ---- x3 = LN(s2, enc_n1) -> R5 ----
    ln_kernel<<<dim3(12288), 256, 0, stream>>>(R(4), en1_g, en1_b, R(5));
    // ---- h = gelu(x3 @ conv1^T + b1) -> R0..R3 (100MB) ----
    gemm256<2><<<dim3(16, 48, 1), 512, 0, stream>>>(R(5), 1024, 0, WS(o_conv1), 1024, 0,
        R(0), 4096, 0, 12288, 1024, conv1_b, nullptr, 0.f, nullptr);
    // ---- s6 = x3 + h @ conv2^T + b2 -> R6 ----
    gemm256<3><<<dim3(4, 48, 1), 512, 0, stream>>>(R(0), 4096, 0, WS(o_conv2), 4096, 0,
        R(6), 1024, 0, 12288, 4096, conv2_b, R(5), 0.f, nullptr);
    // ---- x5 = LN(LN(s6, enc_n2), ln1) -> R7 ----
    ln2_kernel<<<dim3(12288), 256, 0, stream>>>(R(6), en2_g, en2_b, ln1_g, ln1_b, R(7));
    // ---- q = (x5 @ wq^T) * 0.125 -> R0 ----
    gemm256<4><<<dim3(4, 48, 1), 512, 0, stream>>>(R(7), 1024, 0, WS(o_wq), 1024, 0,
        R(0), 1024, 0, 12288, 1024, nullptr, nullptr, 0.125f, nullptr);
    // ---- conds bf16 -> R4 (free after ln) ----
    cvt_kernel<<<dim3(512), dim3(256), 0, stream>>>(conds, R(4), 6291456 / 4);
    // ---- cond = conds @ w_cond^T + b_cond -> R5 ----
    gemm256<1><<<dim3(4, 48, 1), 512, 0, stream>>>(R(4), 512, 0, WS(o_wcond), 512, 0,
        R(5), 1024, 0, 12288, 512, b_cond, nullptr, 0.f, nullptr);
    // ---- k,v merged: cond @ [wk;wv]^T -> C [12288][2048] spanning R1,R2 ----
    gemm256<0><<<dim3(8, 48, 1), 512, 0, stream>>>(R(5), 1024, 0, WS(o_wkv), 1024, 0,
        R(1), 2048, 0, 12288, 1024, nullptr, nullptr, 0.f, nullptr);
    // ---- attention -> o R3 ----
    attn_kernel<<<dim3(3, 16, 64), 256, 0, stream>>>(R(0), R(1), R(1) + 1024, R(3), 2048);
    // ---- xo = o @ wo^T + bo -> R6 ----
    gemm256<1><<<dim3(4, 48, 1), 512, 0, stream>>>(R(3), 1024, 0, WS(o_wo), 1024, 0,
        R(6), 1024, 0, 12288, 1024, bo, nullptr, 0.f, nullptr);
    // ---- gated = tanh/sigmoid(LN(xo, ln2)) -> R4 [12288][512] ----
    lngate_kernel<<<dim3(12288), 256, 0, stream>>>(R(6), ln2_g, ln2_b, R(4));
    // ---- final: z = gated @ w_out^T + b_out; leaky; split out/skip -> d_out (f32) ----
    gemm256<5><<<dim3(8, 48, 1), 512, 0, stream>>>(R(4), 512, 0, WS(o_wout), 512, 0,
        d_out, 1024, 0, 12288, 512, b_out, nullptr, 0.f, x_f);
}